// Round 2
// baseline (2496.540 us; speedup 1.0000x reference)
//
#include <hip/hip_runtime.h>

// Problem constants (fixed by the reference)
constexpr int N = 50000;
constexpr int E = 800000;
constexpr int G = 1024;

// ---------------------------------------------------------------------------
// agg1: per-edge scatter for layer 1.
//   deg[d]   += 1
//   agg_e[d] += edge_attr[e]      (16 floats)
//   agg_x[d] += x[src[e]]         (64 floats)
// 16 threads per edge, float4 granularity.
// ---------------------------------------------------------------------------
__global__ __launch_bounds__(256) void agg1_kernel(
    const float* __restrict__ x, const int* __restrict__ src,
    const int* __restrict__ dst, const float* __restrict__ ea,
    float* __restrict__ deg, float* __restrict__ agg_e,
    float* __restrict__ agg_x)
{
    int tid = blockIdx.x * 256 + threadIdx.x;
    int e = tid >> 4;
    int l = tid & 15;
    if (e >= E) return;
    int s = src[e], d = dst[e];
    float4 xv = ((const float4*)(x + (size_t)s * 64))[l];
    float* ax = agg_x + (size_t)d * 64 + l * 4;
    atomicAdd(ax + 0, xv.x);
    atomicAdd(ax + 1, xv.y);
    atomicAdd(ax + 2, xv.z);
    atomicAdd(ax + 3, xv.w);
    if (l < 4) {
        float4 ev = ((const float4*)(ea + (size_t)e * 16))[l];
        float* ae = agg_e + (size_t)d * 16 + l * 4;
        atomicAdd(ae + 0, ev.x);
        atomicAdd(ae + 1, ev.y);
        atomicAdd(ae + 2, ev.z);
        atomicAdd(ae + 3, ev.w);
    }
    if (l == 0) atomicAdd(deg + d, 1.0f);
}

// ---------------------------------------------------------------------------
// agg2: per-edge scatter for layer 2: agg_h[d] += h1[src[e]]  (128 floats)
// 32 threads per edge, float4 granularity.
// ---------------------------------------------------------------------------
__global__ __launch_bounds__(256) void agg2_kernel(
    const float* __restrict__ h1, const int* __restrict__ src,
    const int* __restrict__ dst, float* __restrict__ agg_h)
{
    int tid = blockIdx.x * 256 + threadIdx.x;
    int e = tid >> 5;
    int l = tid & 31;
    if (e >= E) return;
    int s = src[e], d = dst[e];
    float4 v = ((const float4*)(h1 + (size_t)s * 128))[l];
    float* a = agg_h + (size_t)d * 128 + l * 4;
    atomicAdd(a + 0, v.x);
    atomicAdd(a + 1, v.y);
    atomicAdd(a + 2, v.z);
    atomicAdd(a + 3, v.w);
}

// ---------------------------------------------------------------------------
// combine1: h1 = relu(bn1(relu( A1 @ W1 + deg*b1 )))
// A1 row i = [ (deg_i+1)*x_i | agg_x_i + x_i | agg_e_i + 1 ]   (K=144)
// 16 nodes per block (N=50000 => 3125 blocks), 256 threads.
// ---------------------------------------------------------------------------
__global__ __launch_bounds__(256) void combine1_kernel(
    const float* __restrict__ x, const float* __restrict__ deg,
    const float* __restrict__ agg_e, const float* __restrict__ agg_x,
    const float* __restrict__ W, const float* __restrict__ bias,
    const float* __restrict__ bng, const float* __restrict__ bnb,
    float* __restrict__ h1)
{
    __shared__ float sA[16][144];
    __shared__ float sdeg[16];
    const int t = threadIdx.x;
    const int base = blockIdx.x * 16;
    const int n = t >> 4, kk = t & 15;
    const int i = base + n;
    const float dt = deg[i] + 1.0f;   // +1 self loop
    const float* xr = x + (size_t)i * 64;
    const float* axr = agg_x + (size_t)i * 64;
#pragma unroll
    for (int j = 0; j < 4; ++j) {
        int k = kk + j * 16;
        float xv = xr[k];
        sA[n][k] = dt * xv;            // x_i part (summed over deg+1 messages)
        sA[n][64 + k] = axr[k] + xv;   // x_j part (+ self loop)
    }
    sA[n][128 + kk] = agg_e[(size_t)i * 16 + kk] + 1.0f;  // ea part (+ self loop fill=1)
    if (kk == 0) sdeg[n] = dt;
    __syncthreads();

    const int o = t & 127;
    const int hh = t >> 7;
    float acc[8];
#pragma unroll
    for (int j = 0; j < 8; ++j) acc[j] = 0.0f;
#pragma unroll 4
    for (int k = 0; k < 144; ++k) {
        float w = W[k * 128 + o];
#pragma unroll
        for (int j = 0; j < 8; ++j)
            acc[j] = fmaf(sA[2 * j + hh][k], w, acc[j]);
    }
    const float bo = bias[o];
    const float sc = bng[o] * 0.99999500003749974f;  // 1/sqrt(1+1e-5)
    const float bb = bnb[o];
#pragma unroll
    for (int j = 0; j < 8; ++j) {
        int nn = 2 * j + hh;
        float v = fmaxf(acc[j] + sdeg[nn] * bo, 0.0f);  // mp-layer ReLU
        v = fmaxf(v * sc + bb, 0.0f);                   // BN + ReLU
        h1[(size_t)(base + nn) * 128 + o] = v;
    }
}

// ---------------------------------------------------------------------------
// combine2: h2 = relu(bn2(relu( A2 @ W2 + deg*b2 ))) ; ge[batch[i]] += h2
// A2 row i = [ (deg_i+1)*h1_i | agg_h_i + h1_i | agg_e_i + 1 ]   (K=272)
// h2 aliases agg_h: each block stages its agg_h rows to LDS before the
// epilogue overwrites them, and no other block touches those rows.
// ---------------------------------------------------------------------------
__global__ __launch_bounds__(256) void combine2_kernel(
    const float* __restrict__ h1, const float* __restrict__ deg,
    const float* __restrict__ agg_e, const float* __restrict__ agg_h,
    const int* __restrict__ batch,
    const float* __restrict__ W, const float* __restrict__ bias,
    const float* __restrict__ bng, const float* __restrict__ bnb,
    float* __restrict__ h2, float* __restrict__ ge)
{
    __shared__ float sA[16][272];
    __shared__ float sdeg[16];
    __shared__ int sb[16];
    const int t = threadIdx.x;
    const int base = blockIdx.x * 16;
    const int n = t >> 4, kk = t & 15;
    const int i = base + n;
    const float dt = deg[i] + 1.0f;
    const float* hr = h1 + (size_t)i * 128;
    const float* ahr = agg_h + (size_t)i * 128;
#pragma unroll
    for (int j = 0; j < 8; ++j) {
        int k = kk + j * 16;
        float hv = hr[k];
        sA[n][k] = dt * hv;
        sA[n][128 + k] = ahr[k] + hv;
    }
    sA[n][256 + kk] = agg_e[(size_t)i * 16 + kk] + 1.0f;
    if (kk == 0) { sdeg[n] = dt; sb[n] = batch[i]; }
    __syncthreads();

    const int o = t & 127;
    const int hh = t >> 7;
    float acc[8];
#pragma unroll
    for (int j = 0; j < 8; ++j) acc[j] = 0.0f;
#pragma unroll 4
    for (int k = 0; k < 272; ++k) {
        float w = W[k * 128 + o];
#pragma unroll
        for (int j = 0; j < 8; ++j)
            acc[j] = fmaf(sA[2 * j + hh][k], w, acc[j]);
    }
    const float bo = bias[o];
    const float sc = bng[o] * 0.99999500003749974f;
    const float bb = bnb[o];
#pragma unroll
    for (int j = 0; j < 8; ++j) {
        int nn = 2 * j + hh;
        float v = fmaxf(acc[j] + sdeg[nn] * bo, 0.0f);
        v = fmaxf(v * sc + bb, 0.0f);
        h2[(size_t)(base + nn) * 128 + o] = v;
        atomicAdd(&ge[(size_t)sb[nn] * 128 + o], v);  // fused global_add_pool
    }
}

// ---------------------------------------------------------------------------
// final: out = relu([h2 | ge[batch]] @ fc1 + b1) @ fc2 + b2
// 16 nodes per block; node_in and hidden staged in LDS; 4x4 register tiling.
// ---------------------------------------------------------------------------
__global__ __launch_bounds__(256) void final_kernel(
    const float* __restrict__ h2, const float* __restrict__ ge,
    const int* __restrict__ batch,
    const float* __restrict__ W1, const float* __restrict__ b1,
    const float* __restrict__ W2, const float* __restrict__ b2,
    float* __restrict__ out)
{
    __shared__ float sA[16][256];
    __shared__ float sH[16][256];
    const int t = threadIdx.x;
    const int base = blockIdx.x * 16;
    const int n = t >> 4, kk = t & 15;
    const int i = base + n;
    const float* hr = h2 + (size_t)i * 128;
    const float* gr = ge + (size_t)batch[i] * 128;
#pragma unroll
    for (int j = 0; j < 8; ++j) {
        int k = kk + j * 16;
        sA[n][k] = hr[k];
        sA[n][128 + k] = gr[k];
    }
    __syncthreads();

    const int ow = t & 63;
    const int nh = t >> 6;  // 0..3, constant per wave -> LDS broadcasts
    float acc[4][4];
#pragma unroll
    for (int a = 0; a < 4; ++a)
#pragma unroll
        for (int c = 0; c < 4; ++c) acc[a][c] = 0.0f;
#pragma unroll 2
    for (int k = 0; k < 256; ++k) {
        float av[4];
#pragma unroll
        for (int a = 0; a < 4; ++a) av[a] = sA[nh * 4 + a][k];
#pragma unroll
        for (int c = 0; c < 4; ++c) {
            float w = W1[k * 256 + ow + 64 * c];
#pragma unroll
            for (int a = 0; a < 4; ++a)
                acc[a][c] = fmaf(av[a], w, acc[a][c]);
        }
    }
#pragma unroll
    for (int c = 0; c < 4; ++c) {
        float bb = b1[ow + 64 * c];
#pragma unroll
        for (int a = 0; a < 4; ++a)
            sH[nh * 4 + a][ow + 64 * c] = fmaxf(acc[a][c] + bb, 0.0f);
    }
    __syncthreads();

    float acc2[4];
#pragma unroll
    for (int a = 0; a < 4; ++a) acc2[a] = 0.0f;
#pragma unroll 4
    for (int k = 0; k < 256; ++k) {
        float w = W2[k * 64 + ow];
#pragma unroll
        for (int a = 0; a < 4; ++a)
            acc2[a] = fmaf(sH[nh * 4 + a][k], w, acc2[a]);
    }
    const float bo = b2[ow];
#pragma unroll
    for (int a = 0; a < 4; ++a)
        out[(size_t)(base + nh * 4 + a) * 64 + ow] = acc2[a] + bo;
}

// ---------------------------------------------------------------------------
extern "C" void kernel_launch(void* const* d_in, const int* in_sizes, int n_in,
                              void* d_out, int out_size, void* d_ws, size_t ws_size,
                              hipStream_t stream)
{
    const float* x      = (const float*)d_in[0];
    const int*   src    = (const int*)d_in[1];
    const int*   dst    = (const int*)d_in[2];
    const float* eattr  = (const float*)d_in[3];
    const int*   batch  = (const int*)d_in[4];
    const float* lin1_w = (const float*)d_in[5];
    const float* lin1_b = (const float*)d_in[6];
    const float* lin2_w = (const float*)d_in[7];
    const float* lin2_b = (const float*)d_in[8];
    const float* bn1_g  = (const float*)d_in[9];
    const float* bn1_b  = (const float*)d_in[10];
    const float* bn2_g  = (const float*)d_in[11];
    const float* bn2_b  = (const float*)d_in[12];
    const float* fc1_w  = (const float*)d_in[13];
    const float* fc1_b  = (const float*)d_in[14];
    const float* fc2_w  = (const float*)d_in[15];
    const float* fc2_b  = (const float*)d_in[16];
    float* out = (float*)d_out;

    // Workspace layout (floats) — total 273N + 128G ≈ 52.6 MiB (fits 64 MiB ws):
    //   [deg N][agg_e 16N][ge 128G][aggX/aggH 128N][h1 128N]
    // agg_x (layer 1, 64N) aliases the FIRST HALF of the agg_h region; agg_h
    // is re-zeroed between combine1 and agg2. h2 aliases agg_h in combine2
    // (block-local read-before-write, safe).
    float* f     = (float*)d_ws;
    float* deg   = f;
    float* agg_e = f + (size_t)N;
    float* ge    = f + (size_t)17 * N;
    float* agg_x = f + (size_t)17 * N + (size_t)128 * G;   // 64N, dead after combine1
    float* agg_h = agg_x;                                  // 128N
    float* h1    = f + (size_t)145 * N + (size_t)128 * G;  // 128N
    float* h2    = agg_h;

    // Zero pass 1: deg, agg_e, ge, agg_x (contiguous prefix: 81N + 128G floats).
    size_t zero1 = ((size_t)81 * N + (size_t)128 * G) * sizeof(float);
    hipMemsetAsync(d_ws, 0, zero1, stream);

    agg1_kernel<<<(E * 16) / 256, 256, 0, stream>>>(x, src, dst, eattr, deg, agg_e, agg_x);
    combine1_kernel<<<N / 16, 256, 0, stream>>>(x, deg, agg_e, agg_x,
                                                lin1_w, lin1_b, bn1_g, bn1_b, h1);

    // Zero pass 2: agg_h (aliases the now-dead agg_x region), 128N floats.
    hipMemsetAsync((void*)agg_h, 0, (size_t)128 * N * sizeof(float), stream);

    agg2_kernel<<<(E * 32) / 256, 256, 0, stream>>>(h1, src, dst, agg_h);
    combine2_kernel<<<N / 16, 256, 0, stream>>>(h1, deg, agg_e, agg_h, batch,
                                                lin2_w, lin2_b, bn2_g, bn2_b, h2, ge);
    final_kernel<<<N / 16, 256, 0, stream>>>(h2, ge, batch,
                                             fc1_w, fc1_b, fc2_w, fc2_b, out);
}

// Round 3
// 522.000 us; speedup vs baseline: 4.7826x; 4.7826x over previous
//
#include <hip/hip_runtime.h>

// Problem constants (fixed by the reference)
constexpr int N = 50000;
constexpr int E = 800000;
constexpr int G = 1024;

constexpr int SCAN_BLOCKS = (N + 255) / 256;  // 196

// ---------------------------------------------------------------------------
// CSR build step 1: in-degree histogram (int atomics).
// ---------------------------------------------------------------------------
__global__ __launch_bounds__(256) void hist_kernel(
    const int* __restrict__ dst, int* __restrict__ degi)
{
    int e = blockIdx.x * 256 + threadIdx.x;
    if (e < E) atomicAdd(&degi[dst[e]], 1);
}

// ---------------------------------------------------------------------------
// CSR build step 2a: per-block sums of deg (196 partials).
// ---------------------------------------------------------------------------
__global__ __launch_bounds__(256) void scan_bsum_kernel(
    const int* __restrict__ degi, int* __restrict__ bsum)
{
    __shared__ int s[256];
    int t = threadIdx.x;
    int i = blockIdx.x * 256 + t;
    s[t] = (i < N) ? degi[i] : 0;
    __syncthreads();
    for (int off = 128; off > 0; off >>= 1) {
        if (t < off) s[t] += s[t + off];
        __syncthreads();
    }
    if (t == 0) bsum[blockIdx.x] = s[0];
}

// ---------------------------------------------------------------------------
// CSR build step 2b: exclusive scan of the 196 partials (single block).
// ---------------------------------------------------------------------------
__global__ __launch_bounds__(256) void scan_partials_kernel(
    const int* __restrict__ bsum, int* __restrict__ boff)
{
    __shared__ int s[256];
    int t = threadIdx.x;
    int v = (t < SCAN_BLOCKS) ? bsum[t] : 0;
    s[t] = v;
    __syncthreads();
    for (int off = 1; off < 256; off <<= 1) {
        int u = (t >= off) ? s[t - off] : 0;
        __syncthreads();
        s[t] += u;
        __syncthreads();
    }
    if (t < SCAN_BLOCKS) boff[t] = s[t] - v;  // exclusive
}

// ---------------------------------------------------------------------------
// CSR build step 2c: per-element exclusive scan -> offsets; cur = offsets.
// ---------------------------------------------------------------------------
__global__ __launch_bounds__(256) void scan_write_kernel(
    const int* __restrict__ degi, const int* __restrict__ boff,
    int* __restrict__ offs, int* __restrict__ cur)
{
    __shared__ int s[256];
    int t = threadIdx.x;
    int i = blockIdx.x * 256 + t;
    int v = (i < N) ? degi[i] : 0;
    s[t] = v;
    __syncthreads();
    for (int off = 1; off < 256; off <<= 1) {
        int u = (t >= off) ? s[t - off] : 0;
        __syncthreads();
        s[t] += u;
        __syncthreads();
    }
    if (i < N) {
        int o = boff[blockIdx.x] + s[t] - v;
        offs[i] = o;
        cur[i] = o;
    }
}

// ---------------------------------------------------------------------------
// CSR build step 3: scatter (src, edge_id) into dst-sorted order.
// ---------------------------------------------------------------------------
__global__ __launch_bounds__(256) void scatter_kernel(
    const int* __restrict__ src, const int* __restrict__ dst,
    int* __restrict__ cur, int2* __restrict__ sorted)
{
    int e = blockIdx.x * 256 + threadIdx.x;
    if (e >= E) return;
    int d = dst[e];
    int p = atomicAdd(&cur[d], 1);
    sorted[p] = make_int2(src[e], e);
}

// ---------------------------------------------------------------------------
// gather1: agg_x[i] = sum_{e->i} x[src[e]] (64f), agg_e[i] = sum ea[e] (16f).
// One wave per node, lane-per-feature. No atomics.
// ---------------------------------------------------------------------------
__global__ __launch_bounds__(256) void gather1_kernel(
    const float* __restrict__ x, const float* __restrict__ ea,
    const int2* __restrict__ sorted, const int* __restrict__ offs,
    const int* __restrict__ degi,
    float* __restrict__ agg_x, float* __restrict__ agg_e)
{
    int node = blockIdx.x * 4 + (threadIdx.x >> 6);
    int l = threadIdx.x & 63;
    if (node >= N) return;
    int start = offs[node], cnt = degi[node];
    float ax0 = 0.0f, ax1 = 0.0f, ae0 = 0.0f, ae1 = 0.0f;
    int j = 0;
    for (; j + 2 <= cnt; j += 2) {
        int2 e0 = sorted[start + j];
        int2 e1 = sorted[start + j + 1];
        ax0 += x[(size_t)e0.x * 64 + l];
        ax1 += x[(size_t)e1.x * 64 + l];
        if (l < 16) {
            ae0 += ea[(size_t)e0.y * 16 + l];
            ae1 += ea[(size_t)e1.y * 16 + l];
        }
    }
    if (j < cnt) {
        int2 e0 = sorted[start + j];
        ax0 += x[(size_t)e0.x * 64 + l];
        if (l < 16) ae0 += ea[(size_t)e0.y * 16 + l];
    }
    agg_x[(size_t)node * 64 + l] = ax0 + ax1;
    if (l < 16) agg_e[(size_t)node * 16 + l] = ae0 + ae1;
}

// ---------------------------------------------------------------------------
// gather2: agg_h[i] = sum_{e->i} h1[src[e]] (128f). One wave per node,
// float2 per lane. No atomics.
// ---------------------------------------------------------------------------
__global__ __launch_bounds__(256) void gather2_kernel(
    const float* __restrict__ h1, const int2* __restrict__ sorted,
    const int* __restrict__ offs, const int* __restrict__ degi,
    float* __restrict__ agg_h)
{
    int node = blockIdx.x * 4 + (threadIdx.x >> 6);
    int l = threadIdx.x & 63;
    if (node >= N) return;
    int start = offs[node], cnt = degi[node];
    const float2* h = (const float2*)h1;
    float2 a0 = make_float2(0.0f, 0.0f), a1 = make_float2(0.0f, 0.0f);
    int j = 0;
    for (; j + 2 <= cnt; j += 2) {
        int s0 = sorted[start + j].x;
        int s1 = sorted[start + j + 1].x;
        float2 v0 = h[(size_t)s0 * 64 + l];
        float2 v1 = h[(size_t)s1 * 64 + l];
        a0.x += v0.x; a0.y += v0.y;
        a1.x += v1.x; a1.y += v1.y;
    }
    if (j < cnt) {
        int s0 = sorted[start + j].x;
        float2 v0 = h[(size_t)s0 * 64 + l];
        a0.x += v0.x; a0.y += v0.y;
    }
    ((float2*)agg_h)[(size_t)node * 64 + l] = make_float2(a0.x + a1.x, a0.y + a1.y);
}

// ---------------------------------------------------------------------------
// combine1: h1 = relu(bn1(relu( A1 @ W1 + (deg+1)*b1 )))
// A1 row i = [ (deg_i+1)*x_i | agg_x_i + x_i | agg_e_i + 1 ]   (K=144)
// ---------------------------------------------------------------------------
__global__ __launch_bounds__(256) void combine1_kernel(
    const float* __restrict__ x, const int* __restrict__ degi,
    const float* __restrict__ agg_e, const float* __restrict__ agg_x,
    const float* __restrict__ W, const float* __restrict__ bias,
    const float* __restrict__ bng, const float* __restrict__ bnb,
    float* __restrict__ h1)
{
    __shared__ float sA[16][144];
    __shared__ float sdeg[16];
    const int t = threadIdx.x;
    const int base = blockIdx.x * 16;
    const int n = t >> 4, kk = t & 15;
    const int i = base + n;
    const float dt = (float)degi[i] + 1.0f;   // +1 self loop
    const float* xr = x + (size_t)i * 64;
    const float* axr = agg_x + (size_t)i * 64;
#pragma unroll
    for (int j = 0; j < 4; ++j) {
        int k = kk + j * 16;
        float xv = xr[k];
        sA[n][k] = dt * xv;            // x_i part (deg+1 messages)
        sA[n][64 + k] = axr[k] + xv;   // x_j part (+ self loop)
    }
    sA[n][128 + kk] = agg_e[(size_t)i * 16 + kk] + 1.0f;  // ea (+ self loop fill=1)
    if (kk == 0) sdeg[n] = dt;
    __syncthreads();

    const int o = t & 127;
    const int hh = t >> 7;
    float acc[8];
#pragma unroll
    for (int j = 0; j < 8; ++j) acc[j] = 0.0f;
#pragma unroll 4
    for (int k = 0; k < 144; ++k) {
        float w = W[k * 128 + o];
#pragma unroll
        for (int j = 0; j < 8; ++j)
            acc[j] = fmaf(sA[2 * j + hh][k], w, acc[j]);
    }
    const float bo = bias[o];
    const float sc = bng[o] * 0.99999500003749974f;  // 1/sqrt(1+1e-5)
    const float bb = bnb[o];
#pragma unroll
    for (int j = 0; j < 8; ++j) {
        int nn = 2 * j + hh;
        float v = fmaxf(acc[j] + sdeg[nn] * bo, 0.0f);  // mp-layer ReLU
        v = fmaxf(v * sc + bb, 0.0f);                   // BN + ReLU
        h1[(size_t)(base + nn) * 128 + o] = v;
    }
}

// ---------------------------------------------------------------------------
// combine2: h2 = relu(bn2(relu( A2 @ W2 + (deg+1)*b2 ))) ; ge[batch[i]] += h2
// h2 aliases agg_h (block-local read-before-write).
// ---------------------------------------------------------------------------
__global__ __launch_bounds__(256) void combine2_kernel(
    const float* __restrict__ h1, const int* __restrict__ degi,
    const float* __restrict__ agg_e, const float* __restrict__ agg_h,
    const int* __restrict__ batch,
    const float* __restrict__ W, const float* __restrict__ bias,
    const float* __restrict__ bng, const float* __restrict__ bnb,
    float* __restrict__ h2, float* __restrict__ ge)
{
    __shared__ float sA[16][272];
    __shared__ float sdeg[16];
    __shared__ int sb[16];
    const int t = threadIdx.x;
    const int base = blockIdx.x * 16;
    const int n = t >> 4, kk = t & 15;
    const int i = base + n;
    const float dt = (float)degi[i] + 1.0f;
    const float* hr = h1 + (size_t)i * 128;
    const float* ahr = agg_h + (size_t)i * 128;
#pragma unroll
    for (int j = 0; j < 8; ++j) {
        int k = kk + j * 16;
        float hv = hr[k];
        sA[n][k] = dt * hv;
        sA[n][128 + k] = ahr[k] + hv;
    }
    sA[n][256 + kk] = agg_e[(size_t)i * 16 + kk] + 1.0f;
    if (kk == 0) { sdeg[n] = dt; sb[n] = batch[i]; }
    __syncthreads();

    const int o = t & 127;
    const int hh = t >> 7;
    float acc[8];
#pragma unroll
    for (int j = 0; j < 8; ++j) acc[j] = 0.0f;
#pragma unroll 4
    for (int k = 0; k < 272; ++k) {
        float w = W[k * 128 + o];
#pragma unroll
        for (int j = 0; j < 8; ++j)
            acc[j] = fmaf(sA[2 * j + hh][k], w, acc[j]);
    }
    const float bo = bias[o];
    const float sc = bng[o] * 0.99999500003749974f;
    const float bb = bnb[o];
#pragma unroll
    for (int j = 0; j < 8; ++j) {
        int nn = 2 * j + hh;
        float v = fmaxf(acc[j] + sdeg[nn] * bo, 0.0f);
        v = fmaxf(v * sc + bb, 0.0f);
        h2[(size_t)(base + nn) * 128 + o] = v;
        atomicAdd(&ge[(size_t)sb[nn] * 128 + o], v);  // fused global_add_pool
    }
}

// ---------------------------------------------------------------------------
// final: out = relu([h2 | ge[batch]] @ fc1 + b1) @ fc2 + b2
// ---------------------------------------------------------------------------
__global__ __launch_bounds__(256) void final_kernel(
    const float* __restrict__ h2, const float* __restrict__ ge,
    const int* __restrict__ batch,
    const float* __restrict__ W1, const float* __restrict__ b1,
    const float* __restrict__ W2, const float* __restrict__ b2,
    float* __restrict__ out)
{
    __shared__ float sA[16][256];
    __shared__ float sH[16][256];
    const int t = threadIdx.x;
    const int base = blockIdx.x * 16;
    const int n = t >> 4, kk = t & 15;
    const int i = base + n;
    const float* hr = h2 + (size_t)i * 128;
    const float* gr = ge + (size_t)batch[i] * 128;
#pragma unroll
    for (int j = 0; j < 8; ++j) {
        int k = kk + j * 16;
        sA[n][k] = hr[k];
        sA[n][128 + k] = gr[k];
    }
    __syncthreads();

    const int ow = t & 63;
    const int nh = t >> 6;  // 0..3, constant per wave -> LDS broadcasts
    float acc[4][4];
#pragma unroll
    for (int a = 0; a < 4; ++a)
#pragma unroll
        for (int c = 0; c < 4; ++c) acc[a][c] = 0.0f;
#pragma unroll 2
    for (int k = 0; k < 256; ++k) {
        float av[4];
#pragma unroll
        for (int a = 0; a < 4; ++a) av[a] = sA[nh * 4 + a][k];
#pragma unroll
        for (int c = 0; c < 4; ++c) {
            float w = W1[k * 256 + ow + 64 * c];
#pragma unroll
            for (int a = 0; a < 4; ++a)
                acc[a][c] = fmaf(av[a], w, acc[a][c]);
        }
    }
#pragma unroll
    for (int c = 0; c < 4; ++c) {
        float bb = b1[ow + 64 * c];
#pragma unroll
        for (int a = 0; a < 4; ++a)
            sH[nh * 4 + a][ow + 64 * c] = fmaxf(acc[a][c] + bb, 0.0f);
    }
    __syncthreads();

    float acc2[4];
#pragma unroll
    for (int a = 0; a < 4; ++a) acc2[a] = 0.0f;
#pragma unroll 4
    for (int k = 0; k < 256; ++k) {
        float w = W2[k * 64 + ow];
#pragma unroll
        for (int a = 0; a < 4; ++a)
            acc2[a] = fmaf(sH[nh * 4 + a][k], w, acc2[a]);
    }
    const float bo = b2[ow];
#pragma unroll
    for (int a = 0; a < 4; ++a)
        out[(size_t)(base + nh * 4 + a) * 64 + ow] = acc2[a] + bo;
}

// ---------------------------------------------------------------------------
extern "C" void kernel_launch(void* const* d_in, const int* in_sizes, int n_in,
                              void* d_out, int out_size, void* d_ws, size_t ws_size,
                              hipStream_t stream)
{
    const float* x      = (const float*)d_in[0];
    const int*   src    = (const int*)d_in[1];
    const int*   dst    = (const int*)d_in[2];
    const float* eattr  = (const float*)d_in[3];
    const int*   batch  = (const int*)d_in[4];
    const float* lin1_w = (const float*)d_in[5];
    const float* lin1_b = (const float*)d_in[6];
    const float* lin2_w = (const float*)d_in[7];
    const float* lin2_b = (const float*)d_in[8];
    const float* bn1_g  = (const float*)d_in[9];
    const float* bn1_b  = (const float*)d_in[10];
    const float* bn2_g  = (const float*)d_in[11];
    const float* bn2_b  = (const float*)d_in[12];
    const float* fc1_w  = (const float*)d_in[13];
    const float* fc1_b  = (const float*)d_in[14];
    const float* fc2_w  = (const float*)d_in[15];
    const float* fc2_b  = (const float*)d_in[16];
    float* out = (float*)d_out;

    // Workspace layout (bytes). Total ~59.1 MiB.
    //   [degi int N][ge f 128G]  <- the only region that needs zeroing
    //   [offs int N][cur int N][bsum 256][boff 256]
    //   [sorted int2 E][agg_e f 16N][aggX/aggH f 128N][h1 f 128N]
    // agg_x aliases agg_h (layer1 dead before gather2 overwrites); h2
    // aliases agg_h (combine2 block-local read-before-write).
    char* p = (char*)d_ws;
    int*   degi   = (int*)p;
    float* ge     = (float*)(p + (size_t)4 * N);
    int*   offs   = (int*)(p + (size_t)4 * N + (size_t)512 * G);
    int*   cur    = offs + N;
    int*   bsum   = cur + N;
    int*   boff   = bsum + 256;
    int2*  sorted = (int2*)(boff + 256);
    float* agg_e  = (float*)(sorted + E);
    float* agg_x  = agg_e + (size_t)16 * N;
    float* agg_h  = agg_x;                    // 128N region
    float* h1     = agg_h + (size_t)128 * N;
    float* h2     = agg_h;

    // Zero degi + ge (contiguous prefix).
    hipMemsetAsync(d_ws, 0, (size_t)4 * N + (size_t)512 * G, stream);

    // --- CSR build (per call; deterministic work) ---
    hist_kernel<<<(E + 255) / 256, 256, 0, stream>>>(dst, degi);
    scan_bsum_kernel<<<SCAN_BLOCKS, 256, 0, stream>>>(degi, bsum);
    scan_partials_kernel<<<1, 256, 0, stream>>>(bsum, boff);
    scan_write_kernel<<<SCAN_BLOCKS, 256, 0, stream>>>(degi, boff, offs, cur);
    scatter_kernel<<<(E + 255) / 256, 256, 0, stream>>>(src, dst, cur, sorted);

    // --- Layer 1 ---
    gather1_kernel<<<(N + 3) / 4, 256, 0, stream>>>(x, eattr, sorted, offs, degi,
                                                    agg_x, agg_e);
    combine1_kernel<<<N / 16, 256, 0, stream>>>(x, degi, agg_e, agg_x,
                                                lin1_w, lin1_b, bn1_g, bn1_b, h1);

    // --- Layer 2 ---
    gather2_kernel<<<(N + 3) / 4, 256, 0, stream>>>(h1, sorted, offs, degi, agg_h);
    combine2_kernel<<<N / 16, 256, 0, stream>>>(h1, degi, agg_e, agg_h, batch,
                                                lin2_w, lin2_b, bn2_g, bn2_b, h2, ge);

    // --- Readout ---
    final_kernel<<<N / 16, 256, 0, stream>>>(h2, ge, batch,
                                             fc1_w, fc1_b, fc2_w, fc2_b, out);
}

// Round 4
// 429.569 us; speedup vs baseline: 5.8117x; 1.2152x over previous
//
#include <hip/hip_runtime.h>

// Problem constants (fixed by the reference)
constexpr int N = 50000;
constexpr int E = 800000;
constexpr int G = 1024;

constexpr int SCAN_BLOCKS = (N + 255) / 256;  // 196

typedef __attribute__((ext_vector_type(8))) short short8;
typedef __attribute__((ext_vector_type(4))) float f32x4;

__device__ __forceinline__ unsigned short f2bf(float x) {
    union { float f; unsigned u; } v; v.f = x;
    unsigned r = v.u + 0x7FFF + ((v.u >> 16) & 1);  // round-to-nearest-even
    return (unsigned short)(r >> 16);
}

// ---------------------------------------------------------------------------
// CSR build step 1: in-degree histogram (int atomics).
// ---------------------------------------------------------------------------
__global__ __launch_bounds__(256) void hist_kernel(
    const int* __restrict__ dst, int* __restrict__ degi)
{
    int e = blockIdx.x * 256 + threadIdx.x;
    if (e < E) atomicAdd(&degi[dst[e]], 1);
}

// ---------------------------------------------------------------------------
// CSR build step 2a: per-block sums of deg (196 partials).
// ---------------------------------------------------------------------------
__global__ __launch_bounds__(256) void scan_bsum_kernel(
    const int* __restrict__ degi, int* __restrict__ bsum)
{
    __shared__ int s[256];
    int t = threadIdx.x;
    int i = blockIdx.x * 256 + t;
    s[t] = (i < N) ? degi[i] : 0;
    __syncthreads();
    for (int off = 128; off > 0; off >>= 1) {
        if (t < off) s[t] += s[t + off];
        __syncthreads();
    }
    if (t == 0) bsum[blockIdx.x] = s[0];
}

// ---------------------------------------------------------------------------
// CSR build step 2b: exclusive scan of the 196 partials (single block).
// ---------------------------------------------------------------------------
__global__ __launch_bounds__(256) void scan_partials_kernel(
    const int* __restrict__ bsum, int* __restrict__ boff)
{
    __shared__ int s[256];
    int t = threadIdx.x;
    int v = (t < SCAN_BLOCKS) ? bsum[t] : 0;
    s[t] = v;
    __syncthreads();
    for (int off = 1; off < 256; off <<= 1) {
        int u = (t >= off) ? s[t - off] : 0;
        __syncthreads();
        s[t] += u;
        __syncthreads();
    }
    if (t < SCAN_BLOCKS) boff[t] = s[t] - v;  // exclusive
}

// ---------------------------------------------------------------------------
// CSR build step 2c: per-element exclusive scan -> offsets; cur = offsets.
// ---------------------------------------------------------------------------
__global__ __launch_bounds__(256) void scan_write_kernel(
    const int* __restrict__ degi, const int* __restrict__ boff,
    int* __restrict__ offs, int* __restrict__ cur)
{
    __shared__ int s[256];
    int t = threadIdx.x;
    int i = blockIdx.x * 256 + t;
    int v = (i < N) ? degi[i] : 0;
    s[t] = v;
    __syncthreads();
    for (int off = 1; off < 256; off <<= 1) {
        int u = (t >= off) ? s[t - off] : 0;
        __syncthreads();
        s[t] += u;
        __syncthreads();
    }
    if (i < N) {
        int o = boff[blockIdx.x] + s[t] - v;
        offs[i] = o;
        cur[i] = o;
    }
}

// ---------------------------------------------------------------------------
// CSR build step 3: scatter (src, edge_id) into dst-sorted order.
// ---------------------------------------------------------------------------
__global__ __launch_bounds__(256) void scatter_kernel(
    const int* __restrict__ src, const int* __restrict__ dst,
    int* __restrict__ cur, int2* __restrict__ sorted)
{
    int e = blockIdx.x * 256 + threadIdx.x;
    if (e >= E) return;
    int d = dst[e];
    int p = atomicAdd(&cur[d], 1);
    sorted[p] = make_int2(src[e], e);
}

// ---------------------------------------------------------------------------
// prep_weights: fc1_w [256k][256o] -> Wt1 [o][k] bf16; fc2_w [256k][64o] ->
// Wt2 [o][k] bf16. 81920 threads.
// ---------------------------------------------------------------------------
__global__ __launch_bounds__(256) void prep_weights_kernel(
    const float* __restrict__ fc1_w, const float* __restrict__ fc2_w,
    unsigned short* __restrict__ Wt1, unsigned short* __restrict__ Wt2)
{
    int id = blockIdx.x * 256 + threadIdx.x;
    if (id < 65536) {
        int k = id & 255, o = id >> 8;
        Wt1[(size_t)o * 256 + k] = f2bf(fc1_w[(size_t)k * 256 + o]);
    } else if (id < 65536 + 16384) {
        int id2 = id - 65536;
        int k = id2 & 255, o = id2 >> 8;
        Wt2[(size_t)o * 256 + k] = f2bf(fc2_w[(size_t)k * 64 + o]);
    }
}

// ---------------------------------------------------------------------------
// gather1: agg_x[i] = sum_{e->i} x[src[e]] (64f), agg_e[i] = sum ea[e] (16f).
// One wave per node, lane-per-feature. No atomics.
// ---------------------------------------------------------------------------
__global__ __launch_bounds__(256) void gather1_kernel(
    const float* __restrict__ x, const float* __restrict__ ea,
    const int2* __restrict__ sorted, const int* __restrict__ offs,
    const int* __restrict__ degi,
    float* __restrict__ agg_x, float* __restrict__ agg_e)
{
    int node = blockIdx.x * 4 + (threadIdx.x >> 6);
    int l = threadIdx.x & 63;
    if (node >= N) return;
    int start = offs[node], cnt = degi[node];
    float ax0 = 0.0f, ax1 = 0.0f, ae0 = 0.0f, ae1 = 0.0f;
    int j = 0;
    for (; j + 2 <= cnt; j += 2) {
        int2 e0 = sorted[start + j];
        int2 e1 = sorted[start + j + 1];
        ax0 += x[(size_t)e0.x * 64 + l];
        ax1 += x[(size_t)e1.x * 64 + l];
        if (l < 16) {
            ae0 += ea[(size_t)e0.y * 16 + l];
            ae1 += ea[(size_t)e1.y * 16 + l];
        }
    }
    if (j < cnt) {
        int2 e0 = sorted[start + j];
        ax0 += x[(size_t)e0.x * 64 + l];
        if (l < 16) ae0 += ea[(size_t)e0.y * 16 + l];
    }
    agg_x[(size_t)node * 64 + l] = ax0 + ax1;
    if (l < 16) agg_e[(size_t)node * 16 + l] = ae0 + ae1;
}

// ---------------------------------------------------------------------------
// gather2: agg_h[i] = sum_{e->i} h1[src[e]] (128f). One wave per node,
// float2 per lane. No atomics.
// ---------------------------------------------------------------------------
__global__ __launch_bounds__(256) void gather2_kernel(
    const float* __restrict__ h1, const int2* __restrict__ sorted,
    const int* __restrict__ offs, const int* __restrict__ degi,
    float* __restrict__ agg_h)
{
    int node = blockIdx.x * 4 + (threadIdx.x >> 6);
    int l = threadIdx.x & 63;
    if (node >= N) return;
    int start = offs[node], cnt = degi[node];
    const float2* h = (const float2*)h1;
    float2 a0 = make_float2(0.0f, 0.0f), a1 = make_float2(0.0f, 0.0f);
    int j = 0;
    for (; j + 2 <= cnt; j += 2) {
        int s0 = sorted[start + j].x;
        int s1 = sorted[start + j + 1].x;
        float2 v0 = h[(size_t)s0 * 64 + l];
        float2 v1 = h[(size_t)s1 * 64 + l];
        a0.x += v0.x; a0.y += v0.y;
        a1.x += v1.x; a1.y += v1.y;
    }
    if (j < cnt) {
        int s0 = sorted[start + j].x;
        float2 v0 = h[(size_t)s0 * 64 + l];
        a0.x += v0.x; a0.y += v0.y;
    }
    ((float2*)agg_h)[(size_t)node * 64 + l] = make_float2(a0.x + a1.x, a0.y + a1.y);
}

// ---------------------------------------------------------------------------
// combine1: h1 = relu(bn1(relu( A1 @ W1 + (deg+1)*b1 )))
// A1 row i = [ (deg_i+1)*x_i | agg_x_i + x_i | agg_e_i + 1 ]   (K=144)
// ---------------------------------------------------------------------------
__global__ __launch_bounds__(256) void combine1_kernel(
    const float* __restrict__ x, const int* __restrict__ degi,
    const float* __restrict__ agg_e, const float* __restrict__ agg_x,
    const float* __restrict__ W, const float* __restrict__ bias,
    const float* __restrict__ bng, const float* __restrict__ bnb,
    float* __restrict__ h1)
{
    __shared__ float sA[16][144];
    __shared__ float sdeg[16];
    const int t = threadIdx.x;
    const int base = blockIdx.x * 16;
    const int n = t >> 4, kk = t & 15;
    const int i = base + n;
    const float dt = (float)degi[i] + 1.0f;   // +1 self loop
    const float* xr = x + (size_t)i * 64;
    const float* axr = agg_x + (size_t)i * 64;
#pragma unroll
    for (int j = 0; j < 4; ++j) {
        int k = kk + j * 16;
        float xv = xr[k];
        sA[n][k] = dt * xv;            // x_i part (deg+1 messages)
        sA[n][64 + k] = axr[k] + xv;   // x_j part (+ self loop)
    }
    sA[n][128 + kk] = agg_e[(size_t)i * 16 + kk] + 1.0f;  // ea (+ self loop fill=1)
    if (kk == 0) sdeg[n] = dt;
    __syncthreads();

    const int o = t & 127;
    const int hh = t >> 7;
    float acc[8];
#pragma unroll
    for (int j = 0; j < 8; ++j) acc[j] = 0.0f;
#pragma unroll 4
    for (int k = 0; k < 144; ++k) {
        float w = W[k * 128 + o];
#pragma unroll
        for (int j = 0; j < 8; ++j)
            acc[j] = fmaf(sA[2 * j + hh][k], w, acc[j]);
    }
    const float bo = bias[o];
    const float sc = bng[o] * 0.99999500003749974f;  // 1/sqrt(1+1e-5)
    const float bb = bnb[o];
#pragma unroll
    for (int j = 0; j < 8; ++j) {
        int nn = 2 * j + hh;
        float v = fmaxf(acc[j] + sdeg[nn] * bo, 0.0f);  // mp-layer ReLU
        v = fmaxf(v * sc + bb, 0.0f);                   // BN + ReLU
        h1[(size_t)(base + nn) * 128 + o] = v;
    }
}

// ---------------------------------------------------------------------------
// combine2: h2 = relu(bn2(relu( A2 @ W2 + (deg+1)*b2 ))) ; ge[batch[i]] += h2
// h2 aliases agg_h (block-local read-before-write).
// ---------------------------------------------------------------------------
__global__ __launch_bounds__(256) void combine2_kernel(
    const float* __restrict__ h1, const int* __restrict__ degi,
    const float* __restrict__ agg_e, const float* __restrict__ agg_h,
    const int* __restrict__ batch,
    const float* __restrict__ W, const float* __restrict__ bias,
    const float* __restrict__ bng, const float* __restrict__ bnb,
    float* __restrict__ h2, float* __restrict__ ge)
{
    __shared__ float sA[16][272];
    __shared__ float sdeg[16];
    __shared__ int sb[16];
    const int t = threadIdx.x;
    const int base = blockIdx.x * 16;
    const int n = t >> 4, kk = t & 15;
    const int i = base + n;
    const float dt = (float)degi[i] + 1.0f;
    const float* hr = h1 + (size_t)i * 128;
    const float* ahr = agg_h + (size_t)i * 128;
#pragma unroll
    for (int j = 0; j < 8; ++j) {
        int k = kk + j * 16;
        float hv = hr[k];
        sA[n][k] = dt * hv;
        sA[n][128 + k] = ahr[k] + hv;
    }
    sA[n][256 + kk] = agg_e[(size_t)i * 16 + kk] + 1.0f;
    if (kk == 0) { sdeg[n] = dt; sb[n] = batch[i]; }
    __syncthreads();

    const int o = t & 127;
    const int hh = t >> 7;
    float acc[8];
#pragma unroll
    for (int j = 0; j < 8; ++j) acc[j] = 0.0f;
#pragma unroll 4
    for (int k = 0; k < 272; ++k) {
        float w = W[k * 128 + o];
#pragma unroll
        for (int j = 0; j < 8; ++j)
            acc[j] = fmaf(sA[2 * j + hh][k], w, acc[j]);
    }
    const float bo = bias[o];
    const float sc = bng[o] * 0.99999500003749974f;
    const float bb = bnb[o];
#pragma unroll
    for (int j = 0; j < 8; ++j) {
        int nn = 2 * j + hh;
        float v = fmaxf(acc[j] + sdeg[nn] * bo, 0.0f);
        v = fmaxf(v * sc + bb, 0.0f);
        h2[(size_t)(base + nn) * 128 + o] = v;
        atomicAdd(&ge[(size_t)sb[nn] * 128 + o], v);  // fused global_add_pool
    }
}

// ---------------------------------------------------------------------------
// final_mfma: out = relu([h2 | ge[batch]]_bf16 @ Wt1^T + b1) @ Wt2^T + b2
// 16 nodes/block, 4 waves. bf16 MFMA 16x16x32, fp32 accumulate.
// LDS rows are XOR-swizzled (byte ^= (row&7)<<4) to kill the 16-way
// ds_read_b128 conflict of a 512B-stride row-major tile (T2).
// Fragment layouts (m89/m92): A row=lane&15, k=(lane>>4)*8+j;
// B col=lane&15, same k (hence transposed bf16 weights Wt[out][k]);
// D col=lane&15, row=(lane>>4)*4+reg.
// ---------------------------------------------------------------------------
__global__ __launch_bounds__(256) void final_mfma_kernel(
    const float* __restrict__ h2, const float* __restrict__ ge,
    const int* __restrict__ batch,
    const unsigned short* __restrict__ Wt1, const float* __restrict__ b1,
    const unsigned short* __restrict__ Wt2, const float* __restrict__ b2,
    float* __restrict__ out)
{
    __shared__ unsigned short sA[16 * 256];  // node_in bf16, swizzled
    __shared__ unsigned short sH[16 * 256];  // hidden  bf16, swizzled
    const int t = threadIdx.x;
    const int base = blockIdx.x * 16;

    // ---- stage node_in = [h2 | ge[batch]] as bf16 into sA ----
    {
        int n = t >> 4, idx = t & 15;
        const float* srcp = (idx < 8)
            ? (h2 + (size_t)(base + n) * 128 + idx * 16)
            : (ge + (size_t)batch[base + n] * 128 + (idx - 8) * 16);
        float4 v0 = ((const float4*)srcp)[0];
        float4 v1 = ((const float4*)srcp)[1];
        float4 v2 = ((const float4*)srcp)[2];
        float4 v3 = ((const float4*)srcp)[3];
        short8 c0, c1;
        c0[0] = (short)f2bf(v0.x); c0[1] = (short)f2bf(v0.y);
        c0[2] = (short)f2bf(v0.z); c0[3] = (short)f2bf(v0.w);
        c0[4] = (short)f2bf(v1.x); c0[5] = (short)f2bf(v1.y);
        c0[6] = (short)f2bf(v1.z); c0[7] = (short)f2bf(v1.w);
        c1[0] = (short)f2bf(v2.x); c1[1] = (short)f2bf(v2.y);
        c1[2] = (short)f2bf(v2.z); c1[3] = (short)f2bf(v2.w);
        c1[4] = (short)f2bf(v3.x); c1[5] = (short)f2bf(v3.y);
        c1[6] = (short)f2bf(v3.z); c1[7] = (short)f2bf(v3.w);
        int byte0 = n * 512 + idx * 32;
        int swz = (n & 7) << 4;
        *(short8*)((char*)sA + (byte0 ^ swz)) = c0;
        *(short8*)((char*)sA + ((byte0 + 16) ^ swz)) = c1;
    }
    __syncthreads();

    const int w = t >> 6, l = t & 63;
    const int lr = l & 15, lg = l >> 4;

    // ---- fc1: hidden[16][256], wave w owns out cols [64w, 64w+64) ----
    short8 af[8];
    {
        int swz = (lr & 7) << 4;
#pragma unroll
        for (int s = 0; s < 8; ++s)
            af[s] = *(const short8*)((const char*)sA + ((lr * 512 + s * 64 + lg * 16) ^ swz));
    }
#pragma unroll
    for (int tile = 0; tile < 4; ++tile) {
        int outc = w * 64 + tile * 16 + lr;
        const unsigned short* wp = Wt1 + (size_t)outc * 256 + lg * 8;
        short8 bf[8];
#pragma unroll
        for (int s = 0; s < 8; ++s) bf[s] = *(const short8*)(wp + s * 32);
        f32x4 acc = {0.0f, 0.0f, 0.0f, 0.0f};
#pragma unroll
        for (int s = 0; s < 8; ++s)
            acc = __builtin_amdgcn_mfma_f32_16x16x32_bf16(af[s], bf[s], acc, 0, 0, 0);
        // epilogue: bias + ReLU -> bf16 -> sH (swizzled)
        float bb = b1[outc];
#pragma unroll
        for (int r = 0; r < 4; ++r) {
            int node = lg * 4 + r;
            float hv = fmaxf(acc[r] + bb, 0.0f);
            int byte = (node * 512 + outc * 2) ^ ((node & 7) << 4);
            *(unsigned short*)((char*)sH + byte) = f2bf(hv);
        }
    }
    __syncthreads();

    // ---- fc2: out[16][64], wave w owns out cols [16w, 16w+16) ----
    short8 ah[8];
    {
        int swz = (lr & 7) << 4;
#pragma unroll
        for (int s = 0; s < 8; ++s)
            ah[s] = *(const short8*)((const char*)sH + ((lr * 512 + s * 64 + lg * 16) ^ swz));
    }
    {
        int outc = w * 16 + lr;
        const unsigned short* wp = Wt2 + (size_t)outc * 256 + lg * 8;
        f32x4 acc = {0.0f, 0.0f, 0.0f, 0.0f};
#pragma unroll
        for (int s = 0; s < 8; ++s) {
            short8 bfr = *(const short8*)(wp + s * 32);
            acc = __builtin_amdgcn_mfma_f32_16x16x32_bf16(ah[s], bfr, acc, 0, 0, 0);
        }
        float bb = b2[outc];
#pragma unroll
        for (int r = 0; r < 4; ++r) {
            int node = lg * 4 + r;
            out[(size_t)(base + node) * 64 + outc] = acc[r] + bb;
        }
    }
}

// ---------------------------------------------------------------------------
extern "C" void kernel_launch(void* const* d_in, const int* in_sizes, int n_in,
                              void* d_out, int out_size, void* d_ws, size_t ws_size,
                              hipStream_t stream)
{
    const float* x      = (const float*)d_in[0];
    const int*   src    = (const int*)d_in[1];
    const int*   dst    = (const int*)d_in[2];
    const float* eattr  = (const float*)d_in[3];
    const int*   batch  = (const int*)d_in[4];
    const float* lin1_w = (const float*)d_in[5];
    const float* lin1_b = (const float*)d_in[6];
    const float* lin2_w = (const float*)d_in[7];
    const float* lin2_b = (const float*)d_in[8];
    const float* bn1_g  = (const float*)d_in[9];
    const float* bn1_b  = (const float*)d_in[10];
    const float* bn2_g  = (const float*)d_in[11];
    const float* bn2_b  = (const float*)d_in[12];
    const float* fc1_w  = (const float*)d_in[13];
    const float* fc1_b  = (const float*)d_in[14];
    const float* fc2_w  = (const float*)d_in[15];
    const float* fc2_b  = (const float*)d_in[16];
    float* out = (float*)d_out;

    // Workspace layout (bytes). Total ~61.9 MiB.
    //   [degi int N][ge f 128G]  <- the only region that needs zeroing
    //   [offs int N][cur int N][bsum 256][boff 256]
    //   [sorted int2 E][agg_e f 16N][aggX/aggH f 128N][h1 f 128N]
    // agg_x aliases agg_h; h2 aliases agg_h. Wt1/Wt2 (bf16 transposed fc
    // weights, 160KB) alias `cur` (dead after scatter_kernel).
    char* p = (char*)d_ws;
    int*   degi   = (int*)p;
    float* ge     = (float*)(p + (size_t)4 * N);
    int*   offs   = (int*)(p + (size_t)4 * N + (size_t)512 * G);
    int*   cur    = offs + N;
    int*   bsum   = cur + N;
    int*   boff   = bsum + 256;
    int2*  sorted = (int2*)(boff + 256);
    float* agg_e  = (float*)(sorted + E);
    float* agg_x  = agg_e + (size_t)16 * N;
    float* agg_h  = agg_x;                    // 128N region
    float* h1     = agg_h + (size_t)128 * N;
    float* h2     = agg_h;
    unsigned short* Wt1 = (unsigned short*)cur;      // 65536 bf16
    unsigned short* Wt2 = Wt1 + 65536;               // 16384 bf16

    // Zero degi + ge (contiguous prefix).
    hipMemsetAsync(d_ws, 0, (size_t)4 * N + (size_t)512 * G, stream);

    // --- CSR build (per call; deterministic work) ---
    hist_kernel<<<(E + 255) / 256, 256, 0, stream>>>(dst, degi);
    scan_bsum_kernel<<<SCAN_BLOCKS, 256, 0, stream>>>(degi, bsum);
    scan_partials_kernel<<<1, 256, 0, stream>>>(bsum, boff);
    scan_write_kernel<<<SCAN_BLOCKS, 256, 0, stream>>>(degi, boff, offs, cur);
    scatter_kernel<<<(E + 255) / 256, 256, 0, stream>>>(src, dst, cur, sorted);
    prep_weights_kernel<<<320, 256, 0, stream>>>(fc1_w, fc2_w, Wt1, Wt2);

    // --- Layer 1 ---
    gather1_kernel<<<(N + 3) / 4, 256, 0, stream>>>(x, eattr, sorted, offs, degi,
                                                    agg_x, agg_e);
    combine1_kernel<<<N / 16, 256, 0, stream>>>(x, degi, agg_e, agg_x,
                                                lin1_w, lin1_b, bn1_g, bn1_b, h1);

    // --- Layer 2 ---
    gather2_kernel<<<(N + 3) / 4, 256, 0, stream>>>(h1, sorted, offs, degi, agg_h);
    combine2_kernel<<<N / 16, 256, 0, stream>>>(h1, degi, agg_e, agg_h, batch,
                                                lin2_w, lin2_b, bn2_g, bn2_b, h2, ge);

    // --- Readout ---
    final_mfma_kernel<<<N / 16, 256, 0, stream>>>(h2, ge, batch,
                                                  Wt1, fc1_b, Wt2, fc2_b, out);
}

// Round 5
// 305.967 us; speedup vs baseline: 8.1595x; 1.4040x over previous
//
#include <hip/hip_runtime.h>

// Problem constants (fixed by the reference)
constexpr int N = 50000;
constexpr int E = 800000;
constexpr int G = 1024;

constexpr int SCAN_BLOCKS = (N + 255) / 256;  // 196

typedef __attribute__((ext_vector_type(8))) short short8;
typedef __attribute__((ext_vector_type(4))) float f32x4;

__device__ __forceinline__ unsigned short f2bf(float x) {
    union { float f; unsigned u; } v; v.f = x;
    unsigned r = v.u + 0x7FFF + ((v.u >> 16) & 1);  // round-to-nearest-even
    return (unsigned short)(r >> 16);
}
__device__ __forceinline__ float bf2f(unsigned short u) {
    union { unsigned u; float f; } v; v.u = (unsigned)u << 16; return v.f;
}
__device__ __forceinline__ float bflo(unsigned v) {
    union { unsigned u; float f; } x; x.u = v << 16; return x.f;
}
__device__ __forceinline__ float bfhi(unsigned v) {
    union { unsigned u; float f; } x; x.u = v & 0xFFFF0000u; return x.f;
}

// ---------------------------------------------------------------------------
// CSR build step 1: in-degree histogram (int atomics).
// ---------------------------------------------------------------------------
__global__ __launch_bounds__(256) void hist_kernel(
    const int* __restrict__ dst, int* __restrict__ degi)
{
    int e = blockIdx.x * 256 + threadIdx.x;
    if (e < E) atomicAdd(&degi[dst[e]], 1);
}

// ---------------------------------------------------------------------------
// CSR build step 2a/2b/2c: two-level exclusive scan of deg -> offs, cur.
// ---------------------------------------------------------------------------
__global__ __launch_bounds__(256) void scan_bsum_kernel(
    const int* __restrict__ degi, int* __restrict__ bsum)
{
    __shared__ int s[256];
    int t = threadIdx.x;
    int i = blockIdx.x * 256 + t;
    s[t] = (i < N) ? degi[i] : 0;
    __syncthreads();
    for (int off = 128; off > 0; off >>= 1) {
        if (t < off) s[t] += s[t + off];
        __syncthreads();
    }
    if (t == 0) bsum[blockIdx.x] = s[0];
}

__global__ __launch_bounds__(256) void scan_partials_kernel(
    const int* __restrict__ bsum, int* __restrict__ boff)
{
    __shared__ int s[256];
    int t = threadIdx.x;
    int v = (t < SCAN_BLOCKS) ? bsum[t] : 0;
    s[t] = v;
    __syncthreads();
    for (int off = 1; off < 256; off <<= 1) {
        int u = (t >= off) ? s[t - off] : 0;
        __syncthreads();
        s[t] += u;
        __syncthreads();
    }
    if (t < SCAN_BLOCKS) boff[t] = s[t] - v;  // exclusive
}

__global__ __launch_bounds__(256) void scan_write_kernel(
    const int* __restrict__ degi, const int* __restrict__ boff,
    int* __restrict__ offs, int* __restrict__ cur)
{
    __shared__ int s[256];
    int t = threadIdx.x;
    int i = blockIdx.x * 256 + t;
    int v = (i < N) ? degi[i] : 0;
    s[t] = v;
    __syncthreads();
    for (int off = 1; off < 256; off <<= 1) {
        int u = (t >= off) ? s[t - off] : 0;
        __syncthreads();
        s[t] += u;
        __syncthreads();
    }
    if (i < N) {
        int o = boff[blockIdx.x] + s[t] - v;
        offs[i] = o;
        cur[i] = o;
    }
}

// ---------------------------------------------------------------------------
// CSR build step 3: scatter (src, edge_id) into dst-sorted order.
// ---------------------------------------------------------------------------
__global__ __launch_bounds__(256) void scatter_kernel(
    const int* __restrict__ src, const int* __restrict__ dst,
    int* __restrict__ cur, int2* __restrict__ sorted)
{
    int e = blockIdx.x * 256 + threadIdx.x;
    if (e >= E) return;
    int d = dst[e];
    int p = atomicAdd(&cur[d], 1);
    sorted[p] = make_int2(src[e], e);
}

// ---------------------------------------------------------------------------
// gofs: graph offsets via lower_bound on the SORTED batch array.
// ---------------------------------------------------------------------------
__global__ __launch_bounds__(256) void gofs_kernel(
    const int* __restrict__ batch, int* __restrict__ gofs)
{
    int g = blockIdx.x * 256 + threadIdx.x;
    if (g > G) return;
    int lo = 0, hi = N;
    while (lo < hi) {
        int mid = (lo + hi) >> 1;
        if (batch[mid] < g) lo = mid + 1; else hi = mid;
    }
    gofs[g] = lo;
}

// ---------------------------------------------------------------------------
// prep_weights: all four weight matrices -> bf16, transposed [out][k],
// K padded with zeros to a multiple of 32 for the message MLPs.
//   Wl1 [128][160] from lin1_w [144][128]
//   Wl2 [128][288] from lin2_w [272][128]
//   Wt1 [256][256] from fc1_w  [256][256]
//   Wt2 [ 64][256] from fc2_w  [256][64]
// ---------------------------------------------------------------------------
__global__ __launch_bounds__(256) void prep_weights_kernel(
    const float* __restrict__ lin1_w, const float* __restrict__ lin2_w,
    const float* __restrict__ fc1_w, const float* __restrict__ fc2_w,
    unsigned short* __restrict__ Wl1, unsigned short* __restrict__ Wl2,
    unsigned short* __restrict__ Wt1, unsigned short* __restrict__ Wt2)
{
    int id = blockIdx.x * 256 + threadIdx.x;
    if (id < 20480) {                       // 128*160
        int o = id / 160, k = id % 160;
        Wl1[id] = (k < 144) ? f2bf(lin1_w[(size_t)k * 128 + o]) : (unsigned short)0;
    } else if (id < 57344) {                // +128*288
        int id2 = id - 20480;
        int o = id2 / 288, k = id2 % 288;
        Wl2[id2] = (k < 272) ? f2bf(lin2_w[(size_t)k * 128 + o]) : (unsigned short)0;
    } else if (id < 122880) {               // +256*256
        int id2 = id - 57344;
        int k = id2 & 255, o = id2 >> 8;
        Wt1[id2] = f2bf(fc1_w[(size_t)k * 256 + o]);
    } else if (id < 139264) {               // +64*256
        int id2 = id - 122880;
        int k = id2 & 255, o = id2 >> 8;
        Wt2[id2] = f2bf(fc2_w[(size_t)k * 64 + o]);
    }
}

// ---------------------------------------------------------------------------
// gather1: agg_x[i] = sum x[src] (64f fp32), agg_e[i] = sum ea[e] (16f).
// One wave per node. Edge list loaded coalesced into lanes once, indices
// shfl-broadcast (no dependent pointer-chase); 4-deep ILP.
// ---------------------------------------------------------------------------
__global__ __launch_bounds__(256) void gather1_kernel(
    const float* __restrict__ x, const float* __restrict__ ea,
    const int2* __restrict__ sorted, const int* __restrict__ offs,
    const int* __restrict__ degi,
    float* __restrict__ agg_x, float* __restrict__ agg_e)
{
    int node = blockIdx.x * 4 + (threadIdx.x >> 6);
    int l = threadIdx.x & 63;
    if (node >= N) return;
    int start = offs[node], cnt = degi[node];
    float ax0 = 0, ax1 = 0, ax2 = 0, ax3 = 0;
    float ae0 = 0, ae1 = 0, ae2 = 0, ae3 = 0;
    for (int cb = 0; cb < cnt; cb += 64) {
        int m = min(cnt - cb, 64);
        int2 sl = sorted[start + cb + min(l, m - 1)];
        int slx = sl.x, sly = sl.y;
        int j = 0;
        for (; j + 4 <= m; j += 4) {
            int s0 = __shfl(slx, j),     e0 = __shfl(sly, j);
            int s1 = __shfl(slx, j + 1), e1 = __shfl(sly, j + 1);
            int s2 = __shfl(slx, j + 2), e2 = __shfl(sly, j + 2);
            int s3 = __shfl(slx, j + 3), e3 = __shfl(sly, j + 3);
            ax0 += x[(size_t)s0 * 64 + l];
            ax1 += x[(size_t)s1 * 64 + l];
            ax2 += x[(size_t)s2 * 64 + l];
            ax3 += x[(size_t)s3 * 64 + l];
            if (l < 16) {
                ae0 += ea[(size_t)e0 * 16 + l];
                ae1 += ea[(size_t)e1 * 16 + l];
                ae2 += ea[(size_t)e2 * 16 + l];
                ae3 += ea[(size_t)e3 * 16 + l];
            }
        }
        for (; j < m; ++j) {
            int s0 = __shfl(slx, j), e0 = __shfl(sly, j);
            ax0 += x[(size_t)s0 * 64 + l];
            if (l < 16) ae0 += ea[(size_t)e0 * 16 + l];
        }
    }
    agg_x[(size_t)node * 64 + l] = (ax0 + ax1) + (ax2 + ax3);
    if (l < 16) agg_e[(size_t)node * 16 + l] = (ae0 + ae1) + (ae2 + ae3);
}

// ---------------------------------------------------------------------------
// gather2: agg_h[i] = sum h1[src] (128 bf16 -> fp32 accum). One wave/node,
// 2 features per lane (uint = 2 bf16), shfl-broadcast indices, 4-deep ILP.
// ---------------------------------------------------------------------------
__global__ __launch_bounds__(256) void gather2_kernel(
    const unsigned short* __restrict__ h1, const int2* __restrict__ sorted,
    const int* __restrict__ offs, const int* __restrict__ degi,
    float* __restrict__ agg_h)
{
    int node = blockIdx.x * 4 + (threadIdx.x >> 6);
    int l = threadIdx.x & 63;
    if (node >= N) return;
    int start = offs[node], cnt = degi[node];
    const unsigned* h = (const unsigned*)h1;  // 64 uints (=128 bf16) per row
    float a0 = 0, b0 = 0, a1 = 0, b1 = 0, a2 = 0, b2 = 0, a3 = 0, b3 = 0;
    for (int cb = 0; cb < cnt; cb += 64) {
        int m = min(cnt - cb, 64);
        int slx = sorted[start + cb + min(l, m - 1)].x;
        int j = 0;
        for (; j + 4 <= m; j += 4) {
            int s0 = __shfl(slx, j),     s1 = __shfl(slx, j + 1);
            int s2 = __shfl(slx, j + 2), s3 = __shfl(slx, j + 3);
            unsigned v0 = h[(size_t)s0 * 64 + l];
            unsigned v1 = h[(size_t)s1 * 64 + l];
            unsigned v2 = h[(size_t)s2 * 64 + l];
            unsigned v3 = h[(size_t)s3 * 64 + l];
            a0 += bflo(v0); b0 += bfhi(v0);
            a1 += bflo(v1); b1 += bfhi(v1);
            a2 += bflo(v2); b2 += bfhi(v2);
            a3 += bflo(v3); b3 += bfhi(v3);
        }
        for (; j < m; ++j) {
            int s0 = __shfl(slx, j);
            unsigned v0 = h[(size_t)s0 * 64 + l];
            a0 += bflo(v0); b0 += bfhi(v0);
        }
    }
    ((float2*)agg_h)[(size_t)node * 64 + l] =
        make_float2((a0 + a1) + (a2 + a3), (b0 + b1) + (b2 + b3));
}

// ---------------------------------------------------------------------------
// combine1 (MFMA): h1 = relu(bn1(relu( A1 @ W1 + (deg+1)*b1 ))), bf16 out.
// A1 row i = [ dt*x_i | agg_x_i + x_i | agg_e_i + 1 | 0-pad to 160 ]
// 16 nodes/block, 4 waves, mfma_f32_16x16x32_bf16, XOR-swizzled LDS A.
// ---------------------------------------------------------------------------
__global__ __launch_bounds__(256) void combine1_kernel(
    const float* __restrict__ x, const int* __restrict__ degi,
    const float* __restrict__ agg_e, const float* __restrict__ agg_x,
    const unsigned short* __restrict__ Wl1, const float* __restrict__ bias,
    const float* __restrict__ bng, const float* __restrict__ bnb,
    unsigned short* __restrict__ h1)
{
    __shared__ unsigned short sA[16 * 160];  // rows of 320B (mult of 32 -> XOR safe)
    __shared__ float sdeg[16];
    const int t = threadIdx.x;
    const int base = blockIdx.x * 16;
    {
        int n = t >> 4, kk = t & 15;
        int i = base + n;
        float dt = (float)degi[i] + 1.0f;
        const float* xr = x + (size_t)i * 64;
        const float* axr = agg_x + (size_t)i * 64;
        char* sp = (char*)sA;
        int rb = n * 320, swz = (n & 7) << 4;
#pragma unroll
        for (int j = 0; j < 4; ++j) {
            int c = kk + j * 16;
            float xv = xr[c];
            *(unsigned short*)(sp + ((rb + c * 2) ^ swz)) = f2bf(dt * xv);
            *(unsigned short*)(sp + ((rb + (c + 64) * 2) ^ swz)) = f2bf(axr[c] + xv);
        }
        *(unsigned short*)(sp + ((rb + (128 + kk) * 2) ^ swz)) =
            f2bf(agg_e[(size_t)i * 16 + kk] + 1.0f);
        *(unsigned short*)(sp + ((rb + (144 + kk) * 2) ^ swz)) = 0;
        if (kk == 0) sdeg[n] = dt;
    }
    __syncthreads();

    const int w = t >> 6, l = t & 63, lr = l & 15, lg = l >> 4;
    short8 af[5];
    {
        int swz = (lr & 7) << 4;
#pragma unroll
        for (int s = 0; s < 5; ++s)
            af[s] = *(const short8*)((const char*)sA + ((lr * 320 + s * 64 + lg * 16) ^ swz));
    }
#pragma unroll
    for (int tile = 0; tile < 2; ++tile) {
        int outc = (w * 2 + tile) * 16 + lr;
        const unsigned short* wp = Wl1 + (size_t)outc * 160 + lg * 8;
        f32x4 acc = {0.0f, 0.0f, 0.0f, 0.0f};
#pragma unroll
        for (int s = 0; s < 5; ++s) {
            short8 bfr = *(const short8*)(wp + s * 32);
            acc = __builtin_amdgcn_mfma_f32_16x16x32_bf16(af[s], bfr, acc, 0, 0, 0);
        }
        float bo = bias[outc];
        float sc = bng[outc] * 0.99999500003749974f;  // 1/sqrt(1+1e-5)
        float bb = bnb[outc];
#pragma unroll
        for (int r = 0; r < 4; ++r) {
            int node = lg * 4 + r;
            float v = fmaxf(acc[r] + sdeg[node] * bo, 0.0f);
            v = fmaxf(v * sc + bb, 0.0f);
            h1[(size_t)(base + node) * 128 + outc] = f2bf(v);
        }
    }
}

// ---------------------------------------------------------------------------
// combine2 (MFMA): h2 = relu(bn2(relu( A2 @ W2 + (deg+1)*b2 ))), bf16 out.
// A2 row i = [ dt*h1_i | agg_h_i + h1_i | agg_e_i + 1 | 0-pad to 288 ]
// ---------------------------------------------------------------------------
__global__ __launch_bounds__(256) void combine2_kernel(
    const unsigned short* __restrict__ h1, const int* __restrict__ degi,
    const float* __restrict__ agg_e, const float* __restrict__ agg_h,
    const unsigned short* __restrict__ Wl2, const float* __restrict__ bias,
    const float* __restrict__ bng, const float* __restrict__ bnb,
    unsigned short* __restrict__ h2)
{
    __shared__ unsigned short sA[16 * 288];  // rows of 576B (mult of 32)
    __shared__ float sdeg[16];
    const int t = threadIdx.x;
    const int base = blockIdx.x * 16;
    {
        int n = t >> 4, kk = t & 15;
        int i = base + n;
        float dt = (float)degi[i] + 1.0f;
        const unsigned short* hr = h1 + (size_t)i * 128;
        const float* ahr = agg_h + (size_t)i * 128;
        char* sp = (char*)sA;
        int rb = n * 576, swz = (n & 7) << 4;
#pragma unroll
        for (int j = 0; j < 8; ++j) {
            int c = kk + j * 16;
            float hv = bf2f(hr[c]);
            *(unsigned short*)(sp + ((rb + c * 2) ^ swz)) = f2bf(dt * hv);
            *(unsigned short*)(sp + ((rb + (c + 128) * 2) ^ swz)) = f2bf(ahr[c] + hv);
        }
        *(unsigned short*)(sp + ((rb + (256 + kk) * 2) ^ swz)) =
            f2bf(agg_e[(size_t)i * 16 + kk] + 1.0f);
        *(unsigned short*)(sp + ((rb + (272 + kk) * 2) ^ swz)) = 0;
        if (kk == 0) sdeg[n] = dt;
    }
    __syncthreads();

    const int w = t >> 6, l = t & 63, lr = l & 15, lg = l >> 4;
    short8 af[9];
    {
        int swz = (lr & 7) << 4;
#pragma unroll
        for (int s = 0; s < 9; ++s)
            af[s] = *(const short8*)((const char*)sA + ((lr * 576 + s * 64 + lg * 16) ^ swz));
    }
#pragma unroll
    for (int tile = 0; tile < 2; ++tile) {
        int outc = (w * 2 + tile) * 16 + lr;
        const unsigned short* wp = Wl2 + (size_t)outc * 288 + lg * 8;
        f32x4 acc = {0.0f, 0.0f, 0.0f, 0.0f};
#pragma unroll
        for (int s = 0; s < 9; ++s) {
            short8 bfr = *(const short8*)(wp + s * 32);
            acc = __builtin_amdgcn_mfma_f32_16x16x32_bf16(af[s], bfr, acc, 0, 0, 0);
        }
        float bo = bias[outc];
        float sc = bng[outc] * 0.99999500003749974f;
        float bb = bnb[outc];
#pragma unroll
        for (int r = 0; r < 4; ++r) {
            int node = lg * 4 + r;
            float v = fmaxf(acc[r] + sdeg[node] * bo, 0.0f);
            v = fmaxf(v * sc + bb, 0.0f);
            h2[(size_t)(base + node) * 128 + outc] = f2bf(v);
        }
    }
}

// ---------------------------------------------------------------------------
// ge: deterministic global_add_pool. One block per graph; batch is sorted,
// ranges from gofs. Empty graphs write zeros (no memset needed).
// ---------------------------------------------------------------------------
__global__ __launch_bounds__(256) void ge_kernel(
    const unsigned short* __restrict__ h2, const int* __restrict__ gofs,
    float* __restrict__ ge)
{
    __shared__ float s[256];
    int g = blockIdx.x, t = threadIdx.x;
    int lo = gofs[g], hi = gofs[g + 1];
    int col = t & 127, half = t >> 7;
    float acc = 0.0f;
    for (int r = lo + half; r < hi; r += 2)
        acc += bf2f(h2[(size_t)r * 128 + col]);
    s[t] = acc;
    __syncthreads();
    if (t < 128) ge[(size_t)g * 128 + t] = s[t] + s[t + 128];
}

// ---------------------------------------------------------------------------
// final_mfma: out = relu([h2 | ge[batch]]_bf16 @ Wt1^T + b1) @ Wt2^T + b2
// (unchanged from round 4 except h2 is already bf16)
// ---------------------------------------------------------------------------
__global__ __launch_bounds__(256) void final_mfma_kernel(
    const unsigned short* __restrict__ h2, const float* __restrict__ ge,
    const int* __restrict__ batch,
    const unsigned short* __restrict__ Wt1, const float* __restrict__ b1,
    const unsigned short* __restrict__ Wt2, const float* __restrict__ b2,
    float* __restrict__ out)
{
    __shared__ unsigned short sA[16 * 256];  // node_in bf16, swizzled (512B rows)
    __shared__ unsigned short sH[16 * 256];  // hidden  bf16, swizzled
    const int t = threadIdx.x;
    const int base = blockIdx.x * 16;

    {
        int n = t >> 4, idx = t & 15;
        int rb = n * 512, swz = (n & 7) << 4;
        if (idx < 8) {
            const unsigned short* hp = h2 + (size_t)(base + n) * 128 + idx * 16;
            short8 c0 = *(const short8*)hp;
            short8 c1 = *(const short8*)(hp + 8);
            *(short8*)((char*)sA + ((rb + idx * 32) ^ swz)) = c0;
            *(short8*)((char*)sA + ((rb + idx * 32 + 16) ^ swz)) = c1;
        } else {
            const float* gp = ge + (size_t)batch[base + n] * 128 + (idx - 8) * 16;
            float4 v0 = ((const float4*)gp)[0];
            float4 v1 = ((const float4*)gp)[1];
            float4 v2 = ((const float4*)gp)[2];
            float4 v3 = ((const float4*)gp)[3];
            short8 c0, c1;
            c0[0] = (short)f2bf(v0.x); c0[1] = (short)f2bf(v0.y);
            c0[2] = (short)f2bf(v0.z); c0[3] = (short)f2bf(v0.w);
            c0[4] = (short)f2bf(v1.x); c0[5] = (short)f2bf(v1.y);
            c0[6] = (short)f2bf(v1.z); c0[7] = (short)f2bf(v1.w);
            c1[0] = (short)f2bf(v2.x); c1[1] = (short)f2bf(v2.y);
            c1[2] = (short)f2bf(v2.z); c1[3] = (short)f2bf(v2.w);
            c1[4] = (short)f2bf(v3.x); c1[5] = (short)f2bf(v3.y);
            c1[6] = (short)f2bf(v3.z); c1[7] = (short)f2bf(v3.w);
            int b0 = rb + 256 + (idx - 8) * 32;
            *(short8*)((char*)sA + (b0 ^ swz)) = c0;
            *(short8*)((char*)sA + ((b0 + 16) ^ swz)) = c1;
        }
    }
    __syncthreads();

    const int w = t >> 6, l = t & 63;
    const int lr = l & 15, lg = l >> 4;

    short8 af[8];
    {
        int swz = (lr & 7) << 4;
#pragma unroll
        for (int s = 0; s < 8; ++s)
            af[s] = *(const short8*)((const char*)sA + ((lr * 512 + s * 64 + lg * 16) ^ swz));
    }
#pragma unroll
    for (int tile = 0; tile < 4; ++tile) {
        int outc = w * 64 + tile * 16 + lr;
        const unsigned short* wp = Wt1 + (size_t)outc * 256 + lg * 8;
        short8 bf[8];
#pragma unroll
        for (int s = 0; s < 8; ++s) bf[s] = *(const short8*)(wp + s * 32);
        f32x4 acc = {0.0f, 0.0f, 0.0f, 0.0f};
#pragma unroll
        for (int s = 0; s < 8; ++s)
            acc = __builtin_amdgcn_mfma_f32_16x16x32_bf16(af[s], bf[s], acc, 0, 0, 0);
        float bb = b1[outc];
#pragma unroll
        for (int r = 0; r < 4; ++r) {
            int node = lg * 4 + r;
            float hv = fmaxf(acc[r] + bb, 0.0f);
            int byte = (node * 512 + outc * 2) ^ ((node & 7) << 4);
            *(unsigned short*)((char*)sH + byte) = f2bf(hv);
        }
    }
    __syncthreads();

    short8 ah[8];
    {
        int swz = (lr & 7) << 4;
#pragma unroll
        for (int s = 0; s < 8; ++s)
            ah[s] = *(const short8*)((const char*)sH + ((lr * 512 + s * 64 + lg * 16) ^ swz));
    }
    {
        int outc = w * 16 + lr;
        const unsigned short* wp = Wt2 + (size_t)outc * 256 + lg * 8;
        f32x4 acc = {0.0f, 0.0f, 0.0f, 0.0f};
#pragma unroll
        for (int s = 0; s < 8; ++s) {
            short8 bfr = *(const short8*)(wp + s * 32);
            acc = __builtin_amdgcn_mfma_f32_16x16x32_bf16(ah[s], bfr, acc, 0, 0, 0);
        }
        float bb = b2[outc];
#pragma unroll
        for (int r = 0; r < 4; ++r) {
            int node = lg * 4 + r;
            out[(size_t)(base + node) * 64 + outc] = acc[r] + bb;
        }
    }
}

// ---------------------------------------------------------------------------
extern "C" void kernel_launch(void* const* d_in, const int* in_sizes, int n_in,
                              void* d_out, int out_size, void* d_ws, size_t ws_size,
                              hipStream_t stream)
{
    const float* x      = (const float*)d_in[0];
    const int*   src    = (const int*)d_in[1];
    const int*   dst    = (const int*)d_in[2];
    const float* eattr  = (const float*)d_in[3];
    const int*   batch  = (const int*)d_in[4];
    const float* lin1_w = (const float*)d_in[5];
    const float* lin1_b = (const float*)d_in[6];
    const float* lin2_w = (const float*)d_in[7];
    const float* lin2_b = (const float*)d_in[8];
    const float* bn1_g  = (const float*)d_in[9];
    const float* bn1_b  = (const float*)d_in[10];
    const float* bn2_g  = (const float*)d_in[11];
    const float* bn2_b  = (const float*)d_in[12];
    const float* fc1_w  = (const float*)d_in[13];
    const float* fc1_b  = (const float*)d_in[14];
    const float* fc2_w  = (const float*)d_in[15];
    const float* fc2_b  = (const float*)d_in[16];
    float* out = (float*)d_out;

    // Workspace (~62.2 MB, all 16B-aligned regions):
    //   degi(zeroed) | ge | offs | cur | bsum | boff | gofs | sorted |
    //   agg_e | agg-region(agg_x fp32 64N aliased into agg_h fp32 128N) |
    //   h1 bf16 | h2 bf16 | Wl1 | Wl2 | Wt1 | Wt2
    char* p = (char*)d_ws;
    auto alloc = [&](size_t bytes) {
        char* r = p;
        p += (bytes + 15) & ~(size_t)15;
        return r;
    };
    int*   degi   = (int*)alloc((size_t)4 * N);
    float* ge     = (float*)alloc((size_t)512 * G);
    int*   offs   = (int*)alloc((size_t)4 * N);
    int*   cur    = (int*)alloc((size_t)4 * N);
    int*   bsum   = (int*)alloc(1024);
    int*   boff   = (int*)alloc(1024);
    int*   gofs   = (int*)alloc((size_t)4 * (G + 1));
    int2*  sorted = (int2*)alloc((size_t)8 * E);
    float* agg_e  = (float*)alloc((size_t)64 * N);
    float* aggreg = (float*)alloc((size_t)512 * N);   // 128N fp32
    float* agg_x  = aggreg;                           // first 64N (layer 1)
    float* agg_h  = aggreg;                           // full 128N (layer 2)
    unsigned short* h1  = (unsigned short*)alloc((size_t)256 * N);
    unsigned short* h2  = (unsigned short*)alloc((size_t)256 * N);
    unsigned short* Wl1 = (unsigned short*)alloc(2 * 20480);
    unsigned short* Wl2 = (unsigned short*)alloc(2 * 36864);
    unsigned short* Wt1 = (unsigned short*)alloc(2 * 65536);
    unsigned short* Wt2 = (unsigned short*)alloc(2 * 16384);

    // Zero only degi (ge/aggs are fully overwritten every call).
    hipMemsetAsync(degi, 0, (size_t)4 * N, stream);

    // --- CSR build + weight prep (deterministic per call) ---
    hist_kernel<<<(E + 255) / 256, 256, 0, stream>>>(dst, degi);
    scan_bsum_kernel<<<SCAN_BLOCKS, 256, 0, stream>>>(degi, bsum);
    scan_partials_kernel<<<1, 256, 0, stream>>>(bsum, boff);
    scan_write_kernel<<<SCAN_BLOCKS, 256, 0, stream>>>(degi, boff, offs, cur);
    scatter_kernel<<<(E + 255) / 256, 256, 0, stream>>>(src, dst, cur, sorted);
    prep_weights_kernel<<<544, 256, 0, stream>>>(lin1_w, lin2_w, fc1_w, fc2_w,
                                                 Wl1, Wl2, Wt1, Wt2);
    gofs_kernel<<<5, 256, 0, stream>>>(batch, gofs);

    // --- Layer 1 ---
    gather1_kernel<<<(N + 3) / 4, 256, 0, stream>>>(x, eattr, sorted, offs, degi,
                                                    agg_x, agg_e);
    combine1_kernel<<<N / 16, 256, 0, stream>>>(x, degi, agg_e, agg_x,
                                                Wl1, lin1_b, bn1_g, bn1_b, h1);

    // --- Layer 2 ---
    gather2_kernel<<<(N + 3) / 4, 256, 0, stream>>>(h1, sorted, offs, degi, agg_h);
    combine2_kernel<<<N / 16, 256, 0, stream>>>(h1, degi, agg_e, agg_h,
                                                Wl2, lin2_b, bn2_g, bn2_b, h2);

    // --- Pool + readout ---
    ge_kernel<<<G, 256, 0, stream>>>(h2, gofs, ge);
    final_mfma_kernel<<<N / 16, 256, 0, stream>>>(h2, ge, batch,
                                                  Wt1, fc1_b, Wt2, fc2_b, out);
}

// Round 6
// 267.173 us; speedup vs baseline: 9.3443x; 1.1452x over previous
//
#include <hip/hip_runtime.h>

// Problem constants (fixed by the reference)
constexpr int N = 50000;
constexpr int E = 800000;
constexpr int G = 1024;

constexpr int SCAN_BLOCKS = (N + 255) / 256;  // 196

typedef __attribute__((ext_vector_type(8))) short short8;
typedef __attribute__((ext_vector_type(4))) float f32x4;

__device__ __forceinline__ unsigned short f2bf(float x) {
    union { float f; unsigned u; } v; v.f = x;
    unsigned r = v.u + 0x7FFF + ((v.u >> 16) & 1);  // round-to-nearest-even
    return (unsigned short)(r >> 16);
}
__device__ __forceinline__ float bf2f(unsigned short u) {
    union { unsigned u; float f; } v; v.u = (unsigned)u << 16; return v.f;
}
__device__ __forceinline__ float bflo(unsigned v) {
    union { unsigned u; float f; } x; x.u = v << 16; return x.f;
}
__device__ __forceinline__ float bfhi(unsigned v) {
    union { unsigned u; float f; } x; x.u = v & 0xFFFF0000u; return x.f;
}

// ---------------------------------------------------------------------------
// CSR build step 1: in-degree histogram (int atomics).
// ---------------------------------------------------------------------------
__global__ __launch_bounds__(256) void hist_kernel(
    const int* __restrict__ dst, int* __restrict__ degi)
{
    int e = blockIdx.x * 256 + threadIdx.x;
    if (e < E) atomicAdd(&degi[dst[e]], 1);
}

// ---------------------------------------------------------------------------
// CSR build step 2a/2b/2c: two-level exclusive scan of deg -> offs, cur.
// ---------------------------------------------------------------------------
__global__ __launch_bounds__(256) void scan_bsum_kernel(
    const int* __restrict__ degi, int* __restrict__ bsum)
{
    __shared__ int s[256];
    int t = threadIdx.x;
    int i = blockIdx.x * 256 + t;
    s[t] = (i < N) ? degi[i] : 0;
    __syncthreads();
    for (int off = 128; off > 0; off >>= 1) {
        if (t < off) s[t] += s[t + off];
        __syncthreads();
    }
    if (t == 0) bsum[blockIdx.x] = s[0];
}

__global__ __launch_bounds__(256) void scan_partials_kernel(
    const int* __restrict__ bsum, int* __restrict__ boff)
{
    __shared__ int s[256];
    int t = threadIdx.x;
    int v = (t < SCAN_BLOCKS) ? bsum[t] : 0;
    s[t] = v;
    __syncthreads();
    for (int off = 1; off < 256; off <<= 1) {
        int u = (t >= off) ? s[t - off] : 0;
        __syncthreads();
        s[t] += u;
        __syncthreads();
    }
    if (t < SCAN_BLOCKS) boff[t] = s[t] - v;  // exclusive
}

__global__ __launch_bounds__(256) void scan_write_kernel(
    const int* __restrict__ degi, const int* __restrict__ boff,
    int* __restrict__ offs, int* __restrict__ cur)
{
    __shared__ int s[256];
    int t = threadIdx.x;
    int i = blockIdx.x * 256 + t;
    int v = (i < N) ? degi[i] : 0;
    s[t] = v;
    __syncthreads();
    for (int off = 1; off < 256; off <<= 1) {
        int u = (t >= off) ? s[t - off] : 0;
        __syncthreads();
        s[t] += u;
        __syncthreads();
    }
    if (i < N) {
        int o = boff[blockIdx.x] + s[t] - v;
        offs[i] = o;
        cur[i] = o;
    }
}

// ---------------------------------------------------------------------------
// CSR build step 3: scatter (src, edge_id) into dst-sorted order.
// ---------------------------------------------------------------------------
__global__ __launch_bounds__(256) void scatter_kernel(
    const int* __restrict__ src, const int* __restrict__ dst,
    int* __restrict__ cur, int2* __restrict__ sorted)
{
    int e = blockIdx.x * 256 + threadIdx.x;
    if (e >= E) return;
    int d = dst[e];
    int p = atomicAdd(&cur[d], 1);
    sorted[p] = make_int2(src[e], e);
}

// ---------------------------------------------------------------------------
// prep_weights: weights -> bf16 transposed [out][k] (K zero-padded to x32),
// plus graph offsets (lower_bound on sorted batch) in the tail ids.
//   Wl1 [128][160], Wl2 [128][288], Wt1 [256][256], Wt2 [64][256]
// ---------------------------------------------------------------------------
__global__ __launch_bounds__(256) void prep_weights_kernel(
    const float* __restrict__ lin1_w, const float* __restrict__ lin2_w,
    const float* __restrict__ fc1_w, const float* __restrict__ fc2_w,
    const int* __restrict__ batch,
    unsigned short* __restrict__ Wl1, unsigned short* __restrict__ Wl2,
    unsigned short* __restrict__ Wt1, unsigned short* __restrict__ Wt2,
    int* __restrict__ gofs)
{
    int id = blockIdx.x * 256 + threadIdx.x;
    if (id < 20480) {                       // 128*160
        int o = id / 160, k = id % 160;
        Wl1[id] = (k < 144) ? f2bf(lin1_w[(size_t)k * 128 + o]) : (unsigned short)0;
    } else if (id < 57344) {                // +128*288
        int id2 = id - 20480;
        int o = id2 / 288, k = id2 % 288;
        Wl2[id2] = (k < 272) ? f2bf(lin2_w[(size_t)k * 128 + o]) : (unsigned short)0;
    } else if (id < 122880) {               // +256*256
        int id2 = id - 57344;
        int k = id2 & 255, o = id2 >> 8;
        Wt1[id2] = f2bf(fc1_w[(size_t)k * 256 + o]);
    } else if (id < 139264) {               // +64*256
        int id2 = id - 122880;
        int k = id2 & 255, o = id2 >> 8;
        Wt2[id2] = f2bf(fc2_w[(size_t)k * 64 + o]);
    } else if (id < 139264 + G + 1) {       // graph offsets
        int g = id - 139264;
        int lo = 0, hi = N;
        while (lo < hi) {
            int mid = (lo + hi) >> 1;
            if (batch[mid] < g) lo = mid + 1; else hi = mid;
        }
        gofs[g] = lo;
    }
}

// ---------------------------------------------------------------------------
// gather1: agg_x[i] = sum x[src] (64f fp32), agg_e[i] = sum ea[e] (16f).
// One wave per node; edge list loaded coalesced once, shfl-broadcast.
// ---------------------------------------------------------------------------
__global__ __launch_bounds__(256) void gather1_kernel(
    const float* __restrict__ x, const float* __restrict__ ea,
    const int2* __restrict__ sorted, const int* __restrict__ offs,
    const int* __restrict__ degi,
    float* __restrict__ agg_x, float* __restrict__ agg_e)
{
    int node = blockIdx.x * 4 + (threadIdx.x >> 6);
    int l = threadIdx.x & 63;
    if (node >= N) return;
    int start = offs[node], cnt = degi[node];
    float ax0 = 0, ax1 = 0, ax2 = 0, ax3 = 0;
    float ae0 = 0, ae1 = 0, ae2 = 0, ae3 = 0;
    for (int cb = 0; cb < cnt; cb += 64) {
        int m = min(cnt - cb, 64);
        int2 sl = sorted[start + cb + min(l, m - 1)];
        int slx = sl.x, sly = sl.y;
        int j = 0;
        for (; j + 4 <= m; j += 4) {
            int s0 = __shfl(slx, j),     e0 = __shfl(sly, j);
            int s1 = __shfl(slx, j + 1), e1 = __shfl(sly, j + 1);
            int s2 = __shfl(slx, j + 2), e2 = __shfl(sly, j + 2);
            int s3 = __shfl(slx, j + 3), e3 = __shfl(sly, j + 3);
            ax0 += x[(size_t)s0 * 64 + l];
            ax1 += x[(size_t)s1 * 64 + l];
            ax2 += x[(size_t)s2 * 64 + l];
            ax3 += x[(size_t)s3 * 64 + l];
            if (l < 16) {
                ae0 += ea[(size_t)e0 * 16 + l];
                ae1 += ea[(size_t)e1 * 16 + l];
                ae2 += ea[(size_t)e2 * 16 + l];
                ae3 += ea[(size_t)e3 * 16 + l];
            }
        }
        for (; j < m; ++j) {
            int s0 = __shfl(slx, j), e0 = __shfl(sly, j);
            ax0 += x[(size_t)s0 * 64 + l];
            if (l < 16) ae0 += ea[(size_t)e0 * 16 + l];
        }
    }
    agg_x[(size_t)node * 64 + l] = (ax0 + ax1) + (ax2 + ax3);
    if (l < 16) agg_e[(size_t)node * 16 + l] = (ae0 + ae1) + (ae2 + ae3);
}

// ---------------------------------------------------------------------------
// gather2: agg_h[i] = sum h1[src] (128 bf16 -> fp32 accum). One wave/node.
// ---------------------------------------------------------------------------
__global__ __launch_bounds__(256) void gather2_kernel(
    const unsigned short* __restrict__ h1, const int2* __restrict__ sorted,
    const int* __restrict__ offs, const int* __restrict__ degi,
    float* __restrict__ agg_h)
{
    int node = blockIdx.x * 4 + (threadIdx.x >> 6);
    int l = threadIdx.x & 63;
    if (node >= N) return;
    int start = offs[node], cnt = degi[node];
    const unsigned* h = (const unsigned*)h1;  // 64 uints (=128 bf16) per row
    float a0 = 0, b0 = 0, a1 = 0, b1 = 0, a2 = 0, b2 = 0, a3 = 0, b3 = 0;
    for (int cb = 0; cb < cnt; cb += 64) {
        int m = min(cnt - cb, 64);
        int slx = sorted[start + cb + min(l, m - 1)].x;
        int j = 0;
        for (; j + 4 <= m; j += 4) {
            int s0 = __shfl(slx, j),     s1 = __shfl(slx, j + 1);
            int s2 = __shfl(slx, j + 2), s3 = __shfl(slx, j + 3);
            unsigned v0 = h[(size_t)s0 * 64 + l];
            unsigned v1 = h[(size_t)s1 * 64 + l];
            unsigned v2 = h[(size_t)s2 * 64 + l];
            unsigned v3 = h[(size_t)s3 * 64 + l];
            a0 += bflo(v0); b0 += bfhi(v0);
            a1 += bflo(v1); b1 += bfhi(v1);
            a2 += bflo(v2); b2 += bfhi(v2);
            a3 += bflo(v3); b3 += bfhi(v3);
        }
        for (; j < m; ++j) {
            int s0 = __shfl(slx, j);
            unsigned v0 = h[(size_t)s0 * 64 + l];
            a0 += bflo(v0); b0 += bfhi(v0);
        }
    }
    ((float2*)agg_h)[(size_t)node * 64 + l] =
        make_float2((a0 + a1) + (a2 + a3), (b0 + b1) + (b2 + b3));
}

// ---------------------------------------------------------------------------
// combine1 (MFMA, 64 nodes/block, 8 waves): h1 = relu(bn1(relu(A1@W1+dt*b1)))
// A1 row = [ dt*x | agg_x + x | agg_e + 1 | 0-pad ], K=160, rows 320B swz'd.
// Wave w owns out-col tile w (16 cols); B-frags loaded once, 4 node-groups.
// ---------------------------------------------------------------------------
__global__ __launch_bounds__(512) void combine1_kernel(
    const float* __restrict__ x, const int* __restrict__ degi,
    const float* __restrict__ agg_e, const float* __restrict__ agg_x,
    const unsigned short* __restrict__ Wl1, const float* __restrict__ bias,
    const float* __restrict__ bng, const float* __restrict__ bnb,
    unsigned short* __restrict__ h1)
{
    __shared__ unsigned short sA[64 * 160];  // 20KB, rows of 320B (64B-aligned)
    __shared__ float sdeg[64];
    const int t = threadIdx.x;
    const int base = blockIdx.x * 64;
    {
        int n = t >> 3, kk = t & 7;
        int i = min(base + n, N - 1);
        float dt = (float)degi[i] + 1.0f;
        const float* xr = x + (size_t)i * 64;
        const float* axr = agg_x + (size_t)i * 64;
        char* sp = (char*)sA;
        int rb = n * 320, swz = (n & 7) << 4;
#pragma unroll
        for (int j = 0; j < 8; ++j) {
            int c = kk + j * 8;
            float xv = xr[c];
            *(unsigned short*)(sp + ((rb + c * 2) ^ swz)) = f2bf(dt * xv);
            *(unsigned short*)(sp + ((rb + (c + 64) * 2) ^ swz)) = f2bf(axr[c] + xv);
        }
        *(unsigned short*)(sp + ((rb + (128 + kk) * 2) ^ swz)) =
            f2bf(agg_e[(size_t)i * 16 + kk] + 1.0f);
        *(unsigned short*)(sp + ((rb + (136 + kk) * 2) ^ swz)) =
            f2bf(agg_e[(size_t)i * 16 + 8 + kk] + 1.0f);
        *(unsigned short*)(sp + ((rb + (144 + kk) * 2) ^ swz)) = 0;
        *(unsigned short*)(sp + ((rb + (152 + kk) * 2) ^ swz)) = 0;
        if (kk == 0) sdeg[n] = dt;
    }
    __syncthreads();

    const int w = t >> 6, l = t & 63, lr = l & 15, lg = l >> 4;
    const int outc = w * 16 + lr;
    short8 bf[5];
    {
        const unsigned short* wp = Wl1 + (size_t)outc * 160 + lg * 8;
#pragma unroll
        for (int s = 0; s < 5; ++s) bf[s] = *(const short8*)(wp + s * 32);
    }
    const float bo = bias[outc];
    const float sc = bng[outc] * 0.99999500003749974f;  // 1/sqrt(1+1e-5)
    const float bb = bnb[outc];
#pragma unroll
    for (int ng = 0; ng < 4; ++ng) {
        int row = ng * 16 + lr, sw = (row & 7) << 4;
        short8 af[5];
#pragma unroll
        for (int s = 0; s < 5; ++s)
            af[s] = *(const short8*)((const char*)sA + ((row * 320 + s * 64 + lg * 16) ^ sw));
        f32x4 acc = {0.0f, 0.0f, 0.0f, 0.0f};
#pragma unroll
        for (int s = 0; s < 5; ++s)
            acc = __builtin_amdgcn_mfma_f32_16x16x32_bf16(af[s], bf[s], acc, 0, 0, 0);
#pragma unroll
        for (int r = 0; r < 4; ++r) {
            int node = ng * 16 + lg * 4 + r;
            float v = fmaxf(acc[r] + sdeg[node] * bo, 0.0f);
            v = fmaxf(v * sc + bb, 0.0f);
            if (base + node < N)
                h1[(size_t)(base + node) * 128 + outc] = f2bf(v);
        }
    }
}

// ---------------------------------------------------------------------------
// combine2 (MFMA, 64 nodes/block, 8 waves): same template, K=288, rows 576B.
// A2 row = [ dt*h1 | agg_h + h1 | agg_e + 1 | 0-pad ]
// ---------------------------------------------------------------------------
__global__ __launch_bounds__(512) void combine2_kernel(
    const unsigned short* __restrict__ h1, const int* __restrict__ degi,
    const float* __restrict__ agg_e, const float* __restrict__ agg_h,
    const unsigned short* __restrict__ Wl2, const float* __restrict__ bias,
    const float* __restrict__ bng, const float* __restrict__ bnb,
    unsigned short* __restrict__ h2)
{
    __shared__ unsigned short sA[64 * 288];  // 36KB, rows of 576B (64B-aligned)
    __shared__ float sdeg[64];
    const int t = threadIdx.x;
    const int base = blockIdx.x * 64;
    {
        int n = t >> 3, kk = t & 7;
        int i = min(base + n, N - 1);
        float dt = (float)degi[i] + 1.0f;
        const unsigned short* hr = h1 + (size_t)i * 128;
        const float* ahr = agg_h + (size_t)i * 128;
        char* sp = (char*)sA;
        int rb = n * 576, swz = (n & 7) << 4;
#pragma unroll
        for (int j = 0; j < 16; ++j) {
            int c = kk + j * 8;
            float hv = bf2f(hr[c]);
            *(unsigned short*)(sp + ((rb + c * 2) ^ swz)) = f2bf(dt * hv);
            *(unsigned short*)(sp + ((rb + (c + 128) * 2) ^ swz)) = f2bf(ahr[c] + hv);
        }
        *(unsigned short*)(sp + ((rb + (256 + kk) * 2) ^ swz)) =
            f2bf(agg_e[(size_t)i * 16 + kk] + 1.0f);
        *(unsigned short*)(sp + ((rb + (264 + kk) * 2) ^ swz)) =
            f2bf(agg_e[(size_t)i * 16 + 8 + kk] + 1.0f);
        *(unsigned short*)(sp + ((rb + (272 + kk) * 2) ^ swz)) = 0;
        *(unsigned short*)(sp + ((rb + (280 + kk) * 2) ^ swz)) = 0;
        if (kk == 0) sdeg[n] = dt;
    }
    __syncthreads();

    const int w = t >> 6, l = t & 63, lr = l & 15, lg = l >> 4;
    const int outc = w * 16 + lr;
    short8 bf[9];
    {
        const unsigned short* wp = Wl2 + (size_t)outc * 288 + lg * 8;
#pragma unroll
        for (int s = 0; s < 9; ++s) bf[s] = *(const short8*)(wp + s * 32);
    }
    const float bo = bias[outc];
    const float sc = bng[outc] * 0.99999500003749974f;
    const float bb = bnb[outc];
#pragma unroll
    for (int ng = 0; ng < 4; ++ng) {
        int row = ng * 16 + lr, sw = (row & 7) << 4;
        short8 af[9];
#pragma unroll
        for (int s = 0; s < 9; ++s)
            af[s] = *(const short8*)((const char*)sA + ((row * 576 + s * 64 + lg * 16) ^ sw));
        f32x4 acc = {0.0f, 0.0f, 0.0f, 0.0f};
#pragma unroll
        for (int s = 0; s < 9; ++s)
            acc = __builtin_amdgcn_mfma_f32_16x16x32_bf16(af[s], bf[s], acc, 0, 0, 0);
#pragma unroll
        for (int r = 0; r < 4; ++r) {
            int node = ng * 16 + lg * 4 + r;
            float v = fmaxf(acc[r] + sdeg[node] * bo, 0.0f);
            v = fmaxf(v * sc + bb, 0.0f);
            if (base + node < N)
                h2[(size_t)(base + node) * 128 + outc] = f2bf(v);
        }
    }
}

// ---------------------------------------------------------------------------
// ge: deterministic global_add_pool. One block per graph (batch sorted).
// ---------------------------------------------------------------------------
__global__ __launch_bounds__(256) void ge_kernel(
    const unsigned short* __restrict__ h2, const int* __restrict__ gofs,
    float* __restrict__ ge)
{
    __shared__ float s[256];
    int g = blockIdx.x, t = threadIdx.x;
    int lo = gofs[g], hi = gofs[g + 1];
    int col = t & 127, half = t >> 7;
    float acc = 0.0f;
    for (int r = lo + half; r < hi; r += 2)
        acc += bf2f(h2[(size_t)r * 128 + col]);
    s[t] = acc;
    __syncthreads();
    if (t < 128) ge[(size_t)g * 128 + t] = s[t] + s[t + 128];
}

// ---------------------------------------------------------------------------
// final_mfma (64 nodes/block, 8 waves):
//   out = relu([h2 | ge[batch]]_bf16 @ Wt1^T + b1) @ Wt2^T + b2
// fc1: wave w owns tiles {2w,2w+1}; bf loaded once per tile, 4 node-groups.
// fc2: wave w -> col-tile (w&3), node-groups {2*(w>>2), +1}.
// ---------------------------------------------------------------------------
__global__ __launch_bounds__(512) void final_mfma_kernel(
    const unsigned short* __restrict__ h2, const float* __restrict__ ge,
    const int* __restrict__ batch,
    const unsigned short* __restrict__ Wt1, const float* __restrict__ b1,
    const unsigned short* __restrict__ Wt2, const float* __restrict__ b2,
    float* __restrict__ out)
{
    __shared__ unsigned short sA[64 * 256];  // 32KB node_in, 512B rows swz'd
    __shared__ unsigned short sH[64 * 256];  // 32KB hidden
    const int t = threadIdx.x;
    const int base = blockIdx.x * 64;

    {   // stage node_in = [h2 | ge[batch]] as bf16, 8 threads/row
        int n = t >> 3, idx = t & 7;
        int i = min(base + n, N - 1);
        int rb = n * 512, swz = (n & 7) << 4;
        if (idx < 4) {
            const short8* hp = (const short8*)(h2 + (size_t)i * 128 + idx * 32);
#pragma unroll
            for (int q = 0; q < 4; ++q)
                *(short8*)((char*)sA + ((rb + idx * 64 + q * 16) ^ swz)) = hp[q];
        } else {
            const float4* gp = (const float4*)(ge + (size_t)batch[i] * 128 + (idx - 4) * 32);
#pragma unroll
            for (int q = 0; q < 4; ++q) {
                float4 a = gp[2 * q], b = gp[2 * q + 1];
                short8 c;
                c[0] = (short)f2bf(a.x); c[1] = (short)f2bf(a.y);
                c[2] = (short)f2bf(a.z); c[3] = (short)f2bf(a.w);
                c[4] = (short)f2bf(b.x); c[5] = (short)f2bf(b.y);
                c[6] = (short)f2bf(b.z); c[7] = (short)f2bf(b.w);
                *(short8*)((char*)sA + ((rb + 256 + (idx - 4) * 64 + q * 16) ^ swz)) = c;
            }
        }
    }
    __syncthreads();

    const int w = t >> 6, l = t & 63, lr = l & 15, lg = l >> 4;

    // ---- fc1 ----
#pragma unroll
    for (int tt = 0; tt < 2; ++tt) {
        int outc = (2 * w + tt) * 16 + lr;
        short8 bf[8];
        {
            const unsigned short* wp = Wt1 + (size_t)outc * 256 + lg * 8;
#pragma unroll
            for (int s = 0; s < 8; ++s) bf[s] = *(const short8*)(wp + s * 32);
        }
        float bb = b1[outc];
#pragma unroll
        for (int ng = 0; ng < 4; ++ng) {
            int row = ng * 16 + lr, sw = (row & 7) << 4;
            short8 af[8];
#pragma unroll
            for (int s = 0; s < 8; ++s)
                af[s] = *(const short8*)((const char*)sA + ((row * 512 + s * 64 + lg * 16) ^ sw));
            f32x4 acc = {0.0f, 0.0f, 0.0f, 0.0f};
#pragma unroll
            for (int s = 0; s < 8; ++s)
                acc = __builtin_amdgcn_mfma_f32_16x16x32_bf16(af[s], bf[s], acc, 0, 0, 0);
#pragma unroll
            for (int r = 0; r < 4; ++r) {
                int node = ng * 16 + lg * 4 + r;
                float hv = fmaxf(acc[r] + bb, 0.0f);
                int byte = (node * 512 + outc * 2) ^ ((node & 7) << 4);
                *(unsigned short*)((char*)sH + byte) = f2bf(hv);
            }
        }
    }
    __syncthreads();

    // ---- fc2 ----
    {
        int ct = w & 3, ngbase = (w >> 2) * 2;
        int outc = ct * 16 + lr;
        short8 bf[8];
        {
            const unsigned short* wp = Wt2 + (size_t)outc * 256 + lg * 8;
#pragma unroll
            for (int s = 0; s < 8; ++s) bf[s] = *(const short8*)(wp + s * 32);
        }
        float bb = b2[outc];
#pragma unroll
        for (int k = 0; k < 2; ++k) {
            int row = (ngbase + k) * 16 + lr, sw = (row & 7) << 4;
            short8 ah[8];
#pragma unroll
            for (int s = 0; s < 8; ++s)
                ah[s] = *(const short8*)((const char*)sH + ((row * 512 + s * 64 + lg * 16) ^ sw));
            f32x4 acc = {0.0f, 0.0f, 0.0f, 0.0f};
#pragma unroll
            for (int s = 0; s < 8; ++s)
                acc = __builtin_amdgcn_mfma_f32_16x16x32_bf16(ah[s], bf[s], acc, 0, 0, 0);
#pragma unroll
            for (int r = 0; r < 4; ++r) {
                int node = (ngbase + k) * 16 + lg * 4 + r;
                if (base + node < N)
                    out[(size_t)(base + node) * 64 + outc] = acc[r] + bb;
            }
        }
    }
}

// ---------------------------------------------------------------------------
extern "C" void kernel_launch(void* const* d_in, const int* in_sizes, int n_in,
                              void* d_out, int out_size, void* d_ws, size_t ws_size,
                              hipStream_t stream)
{
    const float* x      = (const float*)d_in[0];
    const int*   src    = (const int*)d_in[1];
    const int*   dst    = (const int*)d_in[2];
    const float* eattr  = (const float*)d_in[3];
    const int*   batch  = (const int*)d_in[4];
    const float* lin1_w = (const float*)d_in[5];
    const float* lin1_b = (const float*)d_in[6];
    const float* lin2_w = (const float*)d_in[7];
    const float* lin2_b = (const float*)d_in[8];
    const float* bn1_g  = (const float*)d_in[9];
    const float* bn1_b  = (const float*)d_in[10];
    const float* bn2_g  = (const float*)d_in[11];
    const float* bn2_b  = (const float*)d_in[12];
    const float* fc1_w  = (const float*)d_in[13];
    const float* fc1_b  = (const float*)d_in[14];
    const float* fc2_w  = (const float*)d_in[15];
    const float* fc2_b  = (const float*)d_in[16];
    float* out = (float*)d_out;

    // Workspace (~62.2 MB):
    //   degi(zeroed) | ge | offs | cur | bsum | boff | gofs | sorted |
    //   agg_e | agg-region(agg_x 64N aliased into agg_h 128N) |
    //   h1 bf16 | h2 bf16 | Wl1 | Wl2 | Wt1 | Wt2
    char* p = (char*)d_ws;
    auto alloc = [&](size_t bytes) {
        char* r = p;
        p += (bytes + 15) & ~(size_t)15;
        return r;
    };
    int*   degi   = (int*)alloc((size_t)4 * N);
    float* ge     = (float*)alloc((size_t)512 * G);
    int*   offs   = (int*)alloc((size_t)4 * N);
    int*   cur    = (int*)alloc((size_t)4 * N);
    int*   bsum   = (int*)alloc(1024);
    int*   boff   = (int*)alloc(1024);
    int*   gofs   = (int*)alloc((size_t)4 * (G + 1));
    int2*  sorted = (int2*)alloc((size_t)8 * E);
    float* agg_e  = (float*)alloc((size_t)64 * N);
    float* aggreg = (float*)alloc((size_t)512 * N);   // 128N fp32
    float* agg_x  = aggreg;                           // first 64N (layer 1)
    float* agg_h  = aggreg;                           // full 128N (layer 2)
    unsigned short* h1  = (unsigned short*)alloc((size_t)256 * N);
    unsigned short* h2  = (unsigned short*)alloc((size_t)256 * N);
    unsigned short* Wl1 = (unsigned short*)alloc(2 * 20480);
    unsigned short* Wl2 = (unsigned short*)alloc(2 * 36864);
    unsigned short* Wt1 = (unsigned short*)alloc(2 * 65536);
    unsigned short* Wt2 = (unsigned short*)alloc(2 * 16384);

    // Zero only degi (everything else is fully overwritten every call).
    hipMemsetAsync(degi, 0, (size_t)4 * N, stream);

    // --- CSR build + weight prep (deterministic per call) ---
    hist_kernel<<<(E + 255) / 256, 256, 0, stream>>>(dst, degi);
    scan_bsum_kernel<<<SCAN_BLOCKS, 256, 0, stream>>>(degi, bsum);
    scan_partials_kernel<<<1, 256, 0, stream>>>(bsum, boff);
    scan_write_kernel<<<SCAN_BLOCKS, 256, 0, stream>>>(degi, boff, offs, cur);
    scatter_kernel<<<(E + 255) / 256, 256, 0, stream>>>(src, dst, cur, sorted);
    prep_weights_kernel<<<549, 256, 0, stream>>>(lin1_w, lin2_w, fc1_w, fc2_w,
                                                 batch, Wl1, Wl2, Wt1, Wt2, gofs);

    const int NB64 = (N + 63) / 64;  // 782

    // --- Layer 1 ---
    gather1_kernel<<<(N + 3) / 4, 256, 0, stream>>>(x, eattr, sorted, offs, degi,
                                                    agg_x, agg_e);
    combine1_kernel<<<NB64, 512, 0, stream>>>(x, degi, agg_e, agg_x,
                                              Wl1, lin1_b, bn1_g, bn1_b, h1);

    // --- Layer 2 ---
    gather2_kernel<<<(N + 3) / 4, 256, 0, stream>>>(h1, sorted, offs, degi, agg_h);
    combine2_kernel<<<NB64, 512, 0, stream>>>(h1, degi, agg_e, agg_h,
                                              Wl2, lin2_b, bn2_g, bn2_b, h2);

    // --- Pool + readout ---
    ge_kernel<<<G, 256, 0, stream>>>(h2, gofs, ge);
    final_mfma_kernel<<<NB64, 512, 0, stream>>>(h2, ge, batch,
                                                Wt1, fc1_b, Wt2, fc2_b, out);
}